// Round 4
// baseline (922.186 us; speedup 1.0000x reference)
//
#include <hip/hip_runtime.h>
#include <math.h>

#define NN   20000
#define EE   320000
#define RR   4

typedef unsigned short u16;
typedef unsigned int   u32;
typedef __attribute__((ext_vector_type(8))) short short8v;   // 8 bf16 (4 VGPRs)
typedef __attribute__((ext_vector_type(4))) float f32x4;

static __device__ __forceinline__ float lrelu(float v){ return v > 0.f ? v : 0.2f*v; }
static __device__ __forceinline__ float bf2f(u16 u){ return __uint_as_float(((u32)u) << 16); }
static __device__ __forceinline__ u16 f2bf(float f){
  u32 u = __float_as_uint(f);
  u += 0x7fff + ((u >> 16) & 1);        // round-to-nearest-even
  return (u16)(u >> 16);
}
static __device__ __forceinline__ void gload_lds16(const void* g, void* l){
  __builtin_amdgcn_global_load_lds((const __attribute__((address_space(1))) void*)g,
                                   (__attribute__((address_space(3))) void*)l, 16, 0, 0);
}

// ---------------- CSR build (all relations; dst-range passes for L2-local writes) ----------------
__global__ void k_zero_int(int* __restrict__ p, int n){
  int i = blockIdx.x*blockDim.x + threadIdx.x;
  if (i < n) p[i] = 0;
}
__global__ void k_count4(const int* __restrict__ ei, int* __restrict__ deg4, int dlo, int dhi){
  int i = blockIdx.x*blockDim.x + threadIdx.x;
  if (i < RR*EE) {
    int r = i / EE, e = i % EE;
    int d = ei[(size_t)r*2*EE + EE + e];
    if (d >= dlo && d < dhi) atomicAdd(&deg4[r*NN + d], 1);
  }
}
__global__ __launch_bounds__(1024) void k_scan(const int* __restrict__ cnt_all, int* __restrict__ off_all,
                                               int* __restrict__ cur_all, int n){
  const int* cnt = cnt_all + (size_t)blockIdx.x*n;
  int* off = off_all + (size_t)blockIdx.x*(n+1);
  int* cur = cur_all + (size_t)blockIdx.x*n;
  __shared__ int part[1024];
  int t = threadIdx.x;
  int chunk = (n + 1023) >> 10;
  int lo = t*chunk; if (lo > n) lo = n;
  int hi = lo + chunk; if (hi > n) hi = n;
  int s = 0;
  for (int i = lo; i < hi; ++i) s += cnt[i];
  part[t] = s;
  __syncthreads();
  for (int d = 1; d < 1024; d <<= 1) {
    int u = (t >= d) ? part[t-d] : 0;
    __syncthreads();
    part[t] += u;
    __syncthreads();
  }
  int run = (t == 0) ? 0 : part[t-1];
  for (int i = lo; i < hi; ++i) { off[i] = run; cur[i] = run; run += cnt[i]; }
  if (t == 1023) off[n] = part[1023];
}
__global__ void k_scatter4(const int* __restrict__ ei, int* __restrict__ cur4, int* __restrict__ csr4,
                           int dlo, int dhi){
  int i = blockIdx.x*blockDim.x + threadIdx.x;
  if (i < RR*EE) {
    int r = i / EE, e = i % EE;
    int d = ei[(size_t)r*2*EE + EE + e];
    if (d >= dlo && d < dhi) {
      int s = ei[(size_t)r*2*EE + e];
      int p = atomicAdd(&cur4[r*NN + d], 1);
      csr4[(size_t)r*EE + p] = s;
    }
  }
}

// ---------------- prep: f32 -> bf16 cast / transposed-packed weights ----------------
__global__ void k_cast(const float* __restrict__ x, u16* __restrict__ o, int n4){
  int i = blockIdx.x*blockDim.x + threadIdx.x;
  if (i < n4) {
    float4 v = reinterpret_cast<const float4*>(x)[i];
    ushort4 b;
    b.x = f2bf(v.x); b.y = f2bf(v.y); b.z = f2bf(v.z); b.w = f2bf(v.w);
    reinterpret_cast<ushort4*>(o)[i] = b;
  }
}
// dst[r][n][k] bf16 with n in [0,2N): n<N from A (=A^T), else from B. src f32 [r][K][N].
__global__ void k_prep(const float* __restrict__ A, const float* __restrict__ B,
                       u16* __restrict__ dst, int K, int N, int total){
  int i = blockIdx.x*blockDim.x + threadIdx.x;
  if (i >= total) return;
  int k = i % K;
  int n = (i / K) % (2*N);
  int r = i / (K*2*N);
  const float* S = (n < N) ? A : B;
  int nn = (n < N) ? n : n - N;
  dst[i] = f2bf(S[((size_t)r*K + k)*N + nn]);
}

// ---------------- MFMA GEMM: C = act(A0@B0T^T [+ A1@B1T^T] [+bias]); z-batched ----------------
template<int BN, int WM, int WN>
__global__ __launch_bounds__(256) void k_mfma(
    const u16* __restrict__ A0, const u16* __restrict__ BT0,
    const u16* __restrict__ A1, const u16* __restrict__ BT1,
    const float* __restrict__ bias, int M, int K,
    float* __restrict__ Cf, u16* __restrict__ Cb, int ldc, int relu,
    long aZ, long btZ, long cZ, int biasZ)
{
  const int zz = blockIdx.z;
  A0 += (size_t)zz*aZ;
  BT0 += (size_t)zz*btZ;
  if (A1)  A1 += (size_t)zz*aZ;
  if (BT1) BT1 += (size_t)zz*btZ;
  if (bias) bias += (size_t)zz*biasZ;
  if (Cf) Cf += (size_t)zz*cZ;
  if (Cb) Cb += (size_t)zz*cZ;

  constexpr int BM = 128;
  constexpr int FI = WM/16, FJ = WN/16;
  constexpr int NWC = BN/WN;
  constexpr int ACH = BM*32*2/16/256;
  constexpr int BCH = BN*32*2/16/256;
  __shared__ u16 As[BM*32];
  __shared__ u16 Bs[BN*32];
  const int t = threadIdx.x;
  const int lane = t & 63, wid = t >> 6;
  const int wr = wid / NWC, wc = wid % NWC;
  const int bm = blockIdx.x * BM, bn = blockIdx.y * BN;
  const int lr = lane & 15, lk = lane >> 4;

  f32x4 acc[FI][FJ];
  #pragma unroll
  for (int i = 0; i < FI; ++i)
    #pragma unroll
    for (int j = 0; j < FJ; ++j) acc[i][j] = (f32x4)(0.f);

  const int nk = K >> 5;
  const int tot = A1 ? 2*nk : nk;
  char* AsB = (char*)As;
  char* BsB = (char*)Bs;

  for (int s = 0; s < tot; ++s) {
    const u16* Ap = (s < nk) ? A0 : A1;
    const u16* Bp = (s < nk) ? BT0 : BT1;
    const int kk = ((s < nk) ? s : s - nk) << 5;
    #pragma unroll
    for (int i = 0; i < ACH; ++i) {
      int c = t + 256*i;
      int row = c >> 2, sub = c & 3;
      int lsub = sub ^ (row & 3);
      int grow = bm + row; if (grow >= M) grow = M - 1;
      gload_lds16(Ap + (size_t)grow*K + kk + lsub*8, AsB + c*16);
    }
    #pragma unroll
    for (int i = 0; i < BCH; ++i) {
      int c = t + 256*i;
      int row = c >> 2, sub = c & 3;
      int lsub = sub ^ (row & 3);
      gload_lds16(Bp + (size_t)(bn + row)*K + kk + lsub*8, BsB + c*16);
    }
    __syncthreads();
    short8v a[FI], b[FJ];
    #pragma unroll
    for (int i = 0; i < FI; ++i) {
      int row = wr*WM + i*16 + lr;
      int sub = lk ^ (row & 3);
      a[i] = *reinterpret_cast<short8v*>(AsB + row*64 + sub*16);
    }
    #pragma unroll
    for (int j = 0; j < FJ; ++j) {
      int col = wc*WN + j*16 + lr;
      int sub = lk ^ (col & 3);
      b[j] = *reinterpret_cast<short8v*>(BsB + col*64 + sub*16);
    }
    #pragma unroll
    for (int i = 0; i < FI; ++i)
      #pragma unroll
      for (int j = 0; j < FJ; ++j)
        acc[i][j] = __builtin_amdgcn_mfma_f32_16x16x32_bf16(a[i], b[j], acc[i][j], 0, 0, 0);
    __syncthreads();
  }

  #pragma unroll
  for (int i = 0; i < FI; ++i) {
    #pragma unroll
    for (int j = 0; j < FJ; ++j) {
      int col = bn + wc*WN + j*16 + lr;
      float bv = bias ? bias[col] : 0.f;
      #pragma unroll
      for (int q = 0; q < 4; ++q) {
        int row = bm + wr*WM + i*16 + lk*4 + q;
        if (row < M) {
          float v = acc[i][j][q] + bv;
          if (relu) v = fmaxf(v, 0.f);
          if (Cf) Cf[(size_t)row*ldc + col] = v;
          else    Cb[(size_t)row*ldc + col] = f2bf(v);
        }
      }
    }
  }
}

// ---------------- GATv2 attention: one wave per dst, 8-wide predicated unroll; z-batched ----------------
// xl at row*rowStride + z*zColOff + lane*4 ; xr at +256. att/bias/off/csr/out z-strides hardcoded.
__global__ __launch_bounds__(256) void k_gat(
    const u16* __restrict__ xlr, int rowStride, int zColOff,
    const float* __restrict__ att, const float* __restrict__ bias,
    const int* __restrict__ off4, const int* __restrict__ csr4,
    u16* __restrict__ out, int n)
{
  const int z = blockIdx.z;
  int node = blockIdx.x*4 + (threadIdx.x >> 6);
  if (node >= n) return;
  int lane = threadIdx.x & 63;
  const u16* xbase = xlr + (size_t)z*zColOff;
  const int* off = off4 + (size_t)z*(NN+1);
  const int* csr = csr4 + (size_t)z*EE;
  const float* attp = att + (size_t)z*256;
  const float* bp   = bias + (size_t)z*256;
  u16* outp = out + (size_t)z*(size_t)NN*256;

  const size_t co = (size_t)lane*4;
  const u16* selfrow = xbase + (size_t)node*rowStride;
  ushort4 xr4 = *reinterpret_cast<const ushort4*>(selfrow + 256 + co);
  const float xr0 = bf2f(xr4.x), xr1 = bf2f(xr4.y), xr2 = bf2f(xr4.z), xr3 = bf2f(xr4.w);
  float4 av = *reinterpret_cast<const float4*>(attp + lane*4);
  const float L2E = 1.4426950408889634f;
  av.x *= L2E; av.y *= L2E; av.z *= L2E; av.w *= L2E;

  // self loop
  ushort4 xs = *reinterpret_cast<const ushort4*>(selfrow + co);
  float s0c = bf2f(xs.x), s1c = bf2f(xs.y), s2c = bf2f(xs.z), s3c = bf2f(xs.w);
  float ps = av.x*lrelu(s0c+xr0) + av.y*lrelu(s1c+xr1) + av.z*lrelu(s2c+xr2) + av.w*lrelu(s3c+xr3);
  ps += __shfl_xor(ps, 1);
  ps += __shfl_xor(ps, 2);
  ps += __shfl_xor(ps, 4);
  ps += __shfl_xor(ps, 8);
  float m = ps, s = 1.f;
  float a0 = s0c, a1 = s1c, a2 = s2c, a3 = s3c;

  const int e0 = off[node], e1 = off[node+1];
  const int e1m1 = e1 - 1;
  for (int k = e0; k < e1; k += 8) {
    float xv[8][4], p[8];
    #pragma unroll
    for (int j = 0; j < 8; ++j) {
      int kk = k + j;
      int idx = csr[kk < e1 ? kk : e1m1];
      ushort4 v = *reinterpret_cast<const ushort4*>(xbase + (size_t)idx*rowStride + co);
      xv[j][0] = bf2f(v.x); xv[j][1] = bf2f(v.y); xv[j][2] = bf2f(v.z); xv[j][3] = bf2f(v.w);
      p[j] = av.x*lrelu(xv[j][0]+xr0) + av.y*lrelu(xv[j][1]+xr1)
           + av.z*lrelu(xv[j][2]+xr2) + av.w*lrelu(xv[j][3]+xr3);
    }
    #pragma unroll
    for (int j = 0; j < 8; ++j) p[j] += __shfl_xor(p[j], 1);
    #pragma unroll
    for (int j = 0; j < 8; ++j) p[j] += __shfl_xor(p[j], 2);
    #pragma unroll
    for (int j = 0; j < 8; ++j) p[j] += __shfl_xor(p[j], 4);
    #pragma unroll
    for (int j = 0; j < 8; ++j) p[j] += __shfl_xor(p[j], 8);
    #pragma unroll
    for (int j = 0; j < 8; ++j) if (k + j >= e1) p[j] = -INFINITY;
    float mn = m;
    #pragma unroll
    for (int j = 0; j < 8; ++j) mn = fmaxf(mn, p[j]);
    float sc = exp2f(m - mn);
    float w[8];
    #pragma unroll
    for (int j = 0; j < 8; ++j) w[j] = exp2f(p[j] - mn);
    float ws = ((w[0]+w[1])+(w[2]+w[3])) + ((w[4]+w[5])+(w[6]+w[7]));
    s = s*sc + ws;
    float t0 = 0.f, t1 = 0.f, t2 = 0.f, t3 = 0.f;
    #pragma unroll
    for (int j = 0; j < 8; ++j) {
      t0 += w[j]*xv[j][0]; t1 += w[j]*xv[j][1];
      t2 += w[j]*xv[j][2]; t3 += w[j]*xv[j][3];
    }
    a0 = a0*sc + t0; a1 = a1*sc + t1; a2 = a2*sc + t2; a3 = a3*sc + t3;
    m = mn;
  }
  float inv = 1.f / s;
  const float4 bv = *reinterpret_cast<const float4*>(bp + lane*4);
  ushort4 o;
  o.x = f2bf(fmaxf(a0*inv + bv.x, 0.f));
  o.y = f2bf(fmaxf(a1*inv + bv.y, 0.f));
  o.z = f2bf(fmaxf(a2*inv + bv.z, 0.f));
  o.w = f2bf(fmaxf(a3*inv + bv.w, 0.f));
  *reinterpret_cast<ushort4*>(outp + (size_t)node*256 + co) = o;
}

// ---------------- GraphConv neighbor sums (8-wide, z-batched) ----------------
__global__ __launch_bounds__(256) void k_agg256(const u16* __restrict__ x, const int* __restrict__ off4,
                                                const int* __restrict__ csr4, u16* __restrict__ out, int n)
{
  const int z = blockIdx.z;
  int node = blockIdx.x*4 + (threadIdx.x >> 6);
  if (node >= n) return;
  int lane = threadIdx.x & 63;
  const u16* xp = x + (size_t)z*(size_t)NN*256;
  const int* off = off4 + (size_t)z*(NN+1);
  const int* csr = csr4 + (size_t)z*EE;
  u16* outp = out + (size_t)z*(size_t)NN*256;
  const size_t co = (size_t)lane*4;
  float a0 = 0.f, a1 = 0.f, a2 = 0.f, a3 = 0.f;
  const int e0 = off[node], e1 = off[node+1];
  const int e1m1 = e1 - 1;
  for (int k = e0; k < e1; k += 8) {
    #pragma unroll
    for (int j = 0; j < 8; ++j) {
      int kk = k + j;
      int idx = csr[kk < e1 ? kk : e1m1];
      ushort4 v = *reinterpret_cast<const ushort4*>(xp + (size_t)idx*256 + co);
      bool val = kk < e1;
      a0 += val ? bf2f(v.x) : 0.f;
      a1 += val ? bf2f(v.y) : 0.f;
      a2 += val ? bf2f(v.z) : 0.f;
      a3 += val ? bf2f(v.w) : 0.f;
    }
  }
  ushort4 o;
  o.x = f2bf(a0); o.y = f2bf(a1); o.z = f2bf(a2); o.w = f2bf(a3);
  *reinterpret_cast<ushort4*>(outp + (size_t)node*256 + co) = o;
}
__global__ __launch_bounds__(256) void k_agg64(const u16* __restrict__ x, const int* __restrict__ off4,
                                               const int* __restrict__ csr4, u16* __restrict__ out, int n)
{
  const int z = blockIdx.z;
  int node = blockIdx.x*4 + (threadIdx.x >> 6);
  if (node >= n) return;
  int lane = threadIdx.x & 63;
  const u16* xp = x + (size_t)z*(size_t)NN*64;
  const int* off = off4 + (size_t)z*(NN+1);
  const int* csr = csr4 + (size_t)z*EE;
  u16* outp = out + (size_t)z*(size_t)NN*64;
  float a = 0.f;
  const int e0 = off[node], e1 = off[node+1];
  const int e1m1 = e1 - 1;
  for (int k = e0; k < e1; k += 8) {
    #pragma unroll
    for (int j = 0; j < 8; ++j) {
      int kk = k + j;
      int idx = csr[kk < e1 ? kk : e1m1];
      float v = bf2f(xp[(size_t)idx*64 + lane]);
      a += (kk < e1) ? v : 0.f;
    }
  }
  outp[(size_t)node*64 + lane] = f2bf(a);
}

// ---------------- orchestration ----------------
extern "C" void kernel_launch(void* const* d_in, const int* in_sizes, int n_in,
                              void* d_out, int out_size, void* d_ws, size_t ws_size,
                              hipStream_t stream)
{
  const float* x      = (const float*)d_in[0];
  const int*   ei     = (const int*)  d_in[1];
  const float* Wl1    = (const float*)d_in[2];
  const float* Wr1    = (const float*)d_in[3];
  const float* att1   = (const float*)d_in[4];
  const float* b1     = (const float*)d_in[5];
  const float* Wl2    = (const float*)d_in[6];
  const float* Wr2    = (const float*)d_in[7];
  const float* att2   = (const float*)d_in[8];
  const float* b2     = (const float*)d_in[9];
  const float* Wrel3  = (const float*)d_in[10];
  const float* Wroot3 = (const float*)d_in[11];
  const float* b3     = (const float*)d_in[12];
  const float* Wrel4  = (const float*)d_in[13];
  const float* Wroot4 = (const float*)d_in[14];
  const float* b4     = (const float*)d_in[15];
  float* out = (float*)d_out;

  const dim3 thr(256);
  const size_t NB256 = (size_t)NN*256;
  const size_t NB64  = (size_t)NN*64;

  // batched layout size (bytes)
  size_t needB = ((size_t)NN*2048 + NB256*RR + NB256 + NB64*RR + NB64*RR
                  + (size_t)RR*512*256*2 + (size_t)RR*128*256 + (size_t)RR*128*64) * 2
                 + ((size_t)RR*NN*2 + (size_t)RR*(NN+1) + (size_t)RR*EE) * 4;
  bool batched = (ws_size >= needB + 1024);

  if (batched) {
    u16* XLR4  = (u16*)d_ws;                          // [NN][2048]; later aliased as aggb4
    u16* h4    = XLR4 + (size_t)NN*2048;              // [R][NN][256]
    u16* xbf   = h4   + NB256*RR;                     // [NN][256]
    u16* h3b4  = xbf  + NB256;                        // [R][NN][64]
    u16* ag4b4 = h3b4 + NB64*RR;                      // [R][NN][64]
    u16* W1T   = ag4b4 + NB64*RR;                     // [R][512][256] == [2048][256]
    u16* W2T   = W1T + (size_t)RR*512*256;
    u16* W3T   = W2T + (size_t)RR*512*256;
    u16* W4T   = W3T + (size_t)RR*128*256;
    int* deg4  = (int*)(W4T + (size_t)RR*128*64);
    int* off4  = deg4 + RR*NN;
    int* cur4  = off4 + RR*(NN+1);
    int* csr4  = cur4 + RR*NN;
    u16* aggb4 = XLR4;

    k_cast<<<dim3((NN*256/4+255)/256), thr, 0, stream>>>(x, xbf, NN*256/4);
    k_prep<<<dim3((RR*512*256+255)/256), thr, 0, stream>>>(Wl1, Wr1, W1T, 256, 256, RR*512*256);
    k_prep<<<dim3((RR*512*256+255)/256), thr, 0, stream>>>(Wl2, Wr2, W2T, 256, 256, RR*512*256);
    k_prep<<<dim3((RR*128*256+255)/256), thr, 0, stream>>>(Wrel3, Wroot3, W3T, 256, 64, RR*128*256);
    k_prep<<<dim3((RR*128*64+255)/256),  thr, 0, stream>>>(Wrel4, Wroot4, W4T, 64, 64, RR*128*64);

    k_zero_int<<<dim3((RR*NN+255)/256), thr, 0, stream>>>(deg4, RR*NN);
    for (int p = 0; p < 4; ++p)
      k_count4<<<dim3((RR*EE+255)/256), thr, 0, stream>>>(ei, deg4, p*5000, (p+1)*5000);
    k_scan<<<dim3(RR), dim3(1024), 0, stream>>>(deg4, off4, cur4, NN);
    for (int p = 0; p < 4; ++p)
      k_scatter4<<<dim3((RR*EE+255)/256), thr, 0, stream>>>(ei, cur4, csr4, p*5000, (p+1)*5000);

    // L1: one fused GEMM [NN,256] x [256,2048] -> XLR4
    k_mfma<128,64,64><<<dim3(157,16,1), thr, 0, stream>>>(
        xbf, W1T, nullptr, nullptr, nullptr, NN, 256, nullptr, XLR4, 2048, 0, 0, 0, 0, 0);
    k_gat<<<dim3(5000,1,RR), thr, 0, stream>>>(XLR4, 2048, 512, att1, b1, off4, csr4, h4, NN);
    // L2: z-batched GEMMs back into XLR4 slices
    k_mfma<128,64,64><<<dim3(157,4,RR), thr, 0, stream>>>(
        h4, W2T, nullptr, nullptr, nullptr, NN, 256, nullptr, XLR4, 2048, 0,
        (long)NB256, 512*256, 512, 0);
    k_gat<<<dim3(5000,1,RR), thr, 0, stream>>>(XLR4, 2048, 512, att2, b2, off4, csr4, h4, NN);
    // L3
    k_agg256<<<dim3(5000,1,RR), thr, 0, stream>>>(h4, off4, csr4, aggb4, NN);
    k_mfma<64,32,64><<<dim3(157,1,RR), thr, 0, stream>>>(
        aggb4, W3T, h4, W3T + 64*256, b3, NN, 256, nullptr, h3b4, 64, 1,
        (long)NB256, 128*256, (long)NB64, 64);
    // L4
    k_agg64<<<dim3(5000,1,RR), thr, 0, stream>>>(h3b4, off4, csr4, ag4b4, NN);
    k_mfma<64,32,64><<<dim3(157,1,RR), thr, 0, stream>>>(
        ag4b4, W4T, h3b4, W4T + 64*64, b4, NN, 64, out, nullptr, RR*64, 0,
        (long)NB64, 128*64, 64, 64);
  } else {
    // sequential fallback (round-3 layout, ~55 MB)
    u16* XLR  = (u16*)d_ws;                           // [NN][512]
    u16* h    = XLR + (size_t)NN*512;
    u16* xbf  = h   + NB256;
    u16* h3b  = xbf + NB256;
    u16* ag4b = h3b + NB64;
    u16* W1T  = ag4b + NB64;
    u16* W2T  = W1T + (size_t)RR*512*256;
    u16* W3T  = W2T + (size_t)RR*512*256;
    u16* W4T  = W3T + (size_t)RR*128*256;
    int* deg4 = (int*)(W4T + (size_t)RR*128*64);
    int* off4 = deg4 + RR*NN;
    int* cur4 = off4 + RR*(NN+1);
    int* csr4 = cur4 + RR*NN;
    u16* aggb = XLR;

    k_cast<<<dim3((NN*256/4+255)/256), thr, 0, stream>>>(x, xbf, NN*256/4);
    k_prep<<<dim3((RR*512*256+255)/256), thr, 0, stream>>>(Wl1, Wr1, W1T, 256, 256, RR*512*256);
    k_prep<<<dim3((RR*512*256+255)/256), thr, 0, stream>>>(Wl2, Wr2, W2T, 256, 256, RR*512*256);
    k_prep<<<dim3((RR*128*256+255)/256), thr, 0, stream>>>(Wrel3, Wroot3, W3T, 256, 64, RR*128*256);
    k_prep<<<dim3((RR*128*64+255)/256),  thr, 0, stream>>>(Wrel4, Wroot4, W4T, 64, 64, RR*128*64);

    k_zero_int<<<dim3((RR*NN+255)/256), thr, 0, stream>>>(deg4, RR*NN);
    for (int p = 0; p < 4; ++p)
      k_count4<<<dim3((RR*EE+255)/256), thr, 0, stream>>>(ei, deg4, p*5000, (p+1)*5000);
    k_scan<<<dim3(RR), dim3(1024), 0, stream>>>(deg4, off4, cur4, NN);
    for (int p = 0; p < 4; ++p)
      k_scatter4<<<dim3((RR*EE+255)/256), thr, 0, stream>>>(ei, cur4, csr4, p*5000, (p+1)*5000);

    for (int r = 0; r < RR; ++r) {
      const int* off = off4 + (size_t)r*(NN+1);
      const int* csr = csr4 + (size_t)r*EE;
      k_mfma<128,64,64><<<dim3(157,4,1), thr, 0, stream>>>(
          xbf, W1T + (size_t)r*512*256, nullptr, nullptr,
          nullptr, NN, 256, nullptr, XLR, 512, 0, 0, 0, 0, 0);
      k_gat<<<dim3(5000,1,1), thr, 0, stream>>>(XLR, 512, 0, att1 + (size_t)r*256, b1 + (size_t)r*256,
                                                off, csr, h, NN);
      k_mfma<128,64,64><<<dim3(157,4,1), thr, 0, stream>>>(
          h, W2T + (size_t)r*512*256, nullptr, nullptr,
          nullptr, NN, 256, nullptr, XLR, 512, 0, 0, 0, 0, 0);
      k_gat<<<dim3(5000,1,1), thr, 0, stream>>>(XLR, 512, 0, att2 + (size_t)r*256, b2 + (size_t)r*256,
                                                off, csr, h, NN);
      k_agg256<<<dim3(5000,1,1), thr, 0, stream>>>(h, off, csr, aggb, NN);
      k_mfma<64,32,64><<<dim3(157,1,1), thr, 0, stream>>>(
          aggb, W3T + (size_t)r*128*256, h, W3T + (size_t)r*128*256 + 64*256,
          b3 + (size_t)r*64, NN, 256, nullptr, h3b, 64, 1, 0, 0, 0, 0);
      k_agg64<<<dim3(5000,1,1), thr, 0, stream>>>(h3b, off, csr, ag4b, NN);
      k_mfma<64,32,64><<<dim3(157,1,1), thr, 0, stream>>>(
          ag4b, W4T + (size_t)r*128*64, h3b, W4T + (size_t)r*128*64 + 64*64,
          b4 + (size_t)r*64, NN, 64, out + (size_t)r*64, nullptr, RR*64, 0, 0, 0, 0, 0);
    }
  }
}

// Round 5
// 698.819 us; speedup vs baseline: 1.3196x; 1.3196x over previous
//
#include <hip/hip_runtime.h>
#include <math.h>

#define NN   20000
#define EE   320000
#define RR   4

typedef unsigned short u16;
typedef unsigned int   u32;
typedef __attribute__((ext_vector_type(8))) short short8v;   // 8 bf16 (4 VGPRs)
typedef __attribute__((ext_vector_type(4))) float f32x4;

static __device__ __forceinline__ float lrelu(float v){ return fmaxf(v, 0.2f*v); }
static __device__ __forceinline__ float bf2f(u16 u){ return __uint_as_float(((u32)u) << 16); }
static __device__ __forceinline__ u16 f2bf(float f){
  u32 u = __float_as_uint(f);
  u += 0x7fff + ((u >> 16) & 1);        // round-to-nearest-even
  return (u16)(u >> 16);
}
static __device__ __forceinline__ void gload_lds16(const void* g, void* l){
  __builtin_amdgcn_global_load_lds((const __attribute__((address_space(1))) void*)g,
                                   (__attribute__((address_space(3))) void*)l, 16, 0, 0);
}

// ---------------- CSR build ----------------
__global__ void k_zero_int(int* __restrict__ p, int n){
  int i = blockIdx.x*blockDim.x + threadIdx.x;
  if (i < n) p[i] = 0;
}
// count: single pass (counters 320 KB, L2-resident)
__global__ void k_countA(const int* __restrict__ ei, int* __restrict__ deg4){
  int i = blockIdx.x*blockDim.x + threadIdx.x;
  if (i < RR*EE) {
    int r = i / EE, e = i % EE;
    int d = ei[(size_t)r*2*EE + EE + e];
    atomicAdd(&deg4[r*NN + d], 1);
  }
}
__global__ __launch_bounds__(1024) void k_scan(const int* __restrict__ cnt_all, int* __restrict__ off_all,
                                               int* __restrict__ cur_all, int n){
  const int* cnt = cnt_all + (size_t)blockIdx.x*n;
  int* off = off_all + (size_t)blockIdx.x*(n+1);
  int* cur = cur_all + (size_t)blockIdx.x*n;
  __shared__ int part[1024];
  int t = threadIdx.x;
  int chunk = (n + 1023) >> 10;
  int lo = t*chunk; if (lo > n) lo = n;
  int hi = lo + chunk; if (hi > n) hi = n;
  int s = 0;
  for (int i = lo; i < hi; ++i) s += cnt[i];
  part[t] = s;
  __syncthreads();
  for (int d = 1; d < 1024; d <<= 1) {
    int u = (t >= d) ? part[t-d] : 0;
    __syncthreads();
    part[t] += u;
    __syncthreads();
  }
  int run = (t == 0) ? 0 : part[t-1];
  for (int i = lo; i < hi; ++i) { off[i] = run; cur[i] = run; run += cnt[i]; }
  if (t == 1023) off[n] = part[1023];
}
// scatter: 4 dst-range passes keep the random 4B writes L2-local (round-3 fix: 69us -> off top-5)
__global__ void k_scatter4(const int* __restrict__ ei, int* __restrict__ cur4, int* __restrict__ csr4,
                           int dlo, int dhi){
  int i = blockIdx.x*blockDim.x + threadIdx.x;
  if (i < RR*EE) {
    int r = i / EE, e = i % EE;
    int d = ei[(size_t)r*2*EE + EE + e];
    if (d >= dlo && d < dhi) {
      int s = ei[(size_t)r*2*EE + e];
      int p = atomicAdd(&cur4[r*NN + d], 1);
      csr4[(size_t)r*EE + p] = s;
    }
  }
}

// ---------------- prep ----------------
__global__ void k_cast(const float* __restrict__ x, u16* __restrict__ o, int n4){
  int i = blockIdx.x*blockDim.x + threadIdx.x;
  if (i < n4) {
    float4 v = reinterpret_cast<const float4*>(x)[i];
    ushort4 b;
    b.x = f2bf(v.x); b.y = f2bf(v.y); b.z = f2bf(v.z); b.w = f2bf(v.w);
    reinterpret_cast<ushort4*>(o)[i] = b;
  }
}
// dst[r][n][k] bf16 with n in [0,2N): n<N from A (=A^T), else from B. src f32 [r][K][N].
__global__ void k_prep(const float* __restrict__ A, const float* __restrict__ B,
                       u16* __restrict__ dst, int K, int N, int total){
  int i = blockIdx.x*blockDim.x + threadIdx.x;
  if (i >= total) return;
  int k = i % K;
  int n = (i / K) % (2*N);
  int r = i / (K*2*N);
  const float* S = (n < N) ? A : B;
  int nn = (n < N) ? n : n - N;
  dst[i] = f2bf(S[((size_t)r*K + k)*N + nn]);
}

// ---------------- MFMA GEMM: Cb = A@BT^T (bf16 out, raw); z-batched ----------------
// A bf16 [M,K] row-major; BT bf16 [BNtot,K] row-major. BM=128, BN=128, BK=32, 4 waves.
__global__ __launch_bounds__(256) void k_mfma(
    const u16* __restrict__ A, const u16* __restrict__ BT,
    int M, int K, u16* __restrict__ Cb, int ldc,
    long aZ, long btZ, long cZ)
{
  constexpr int BM = 128, BN = 128;
  constexpr int FI = 4, FJ = 4;          // wave tile 64x64, 2x2 waves
  const int zz = blockIdx.z;
  A  += (size_t)zz*aZ;
  BT += (size_t)zz*btZ;
  Cb += (size_t)zz*cZ;

  __shared__ u16 As[BM*32];
  __shared__ u16 Bs[BN*32];
  const int t = threadIdx.x;
  const int lane = t & 63, wid = t >> 6;
  const int wr = wid >> 1, wc = wid & 1;
  const int bm = blockIdx.x * BM, bn = blockIdx.y * BN;
  const int lr = lane & 15, lk = lane >> 4;

  f32x4 acc[FI][FJ];
  #pragma unroll
  for (int i = 0; i < FI; ++i)
    #pragma unroll
    for (int j = 0; j < FJ; ++j) acc[i][j] = (f32x4)(0.f);

  const int nk = K >> 5;
  char* AsB = (char*)As;
  char* BsB = (char*)Bs;

  for (int s = 0; s < nk; ++s) {
    const int kk = s << 5;
    #pragma unroll
    for (int i = 0; i < 2; ++i) {
      int c = t + 256*i;
      int row = c >> 2, sub = c & 3;
      int lsub = sub ^ (row & 3);
      int grow = bm + row; if (grow >= M) grow = M - 1;
      gload_lds16(A + (size_t)grow*K + kk + lsub*8, AsB + c*16);
    }
    #pragma unroll
    for (int i = 0; i < 2; ++i) {
      int c = t + 256*i;
      int row = c >> 2, sub = c & 3;
      int lsub = sub ^ (row & 3);
      gload_lds16(BT + (size_t)(bn + row)*K + kk + lsub*8, BsB + c*16);
    }
    __syncthreads();
    short8v a[FI], b[FJ];
    #pragma unroll
    for (int i = 0; i < FI; ++i) {
      int row = wr*64 + i*16 + lr;
      int sub = lk ^ (row & 3);
      a[i] = *reinterpret_cast<short8v*>(AsB + row*64 + sub*16);
    }
    #pragma unroll
    for (int j = 0; j < FJ; ++j) {
      int col = wc*64 + j*16 + lr;
      int sub = lk ^ (col & 3);
      b[j] = *reinterpret_cast<short8v*>(BsB + col*64 + sub*16);
    }
    #pragma unroll
    for (int i = 0; i < FI; ++i)
      #pragma unroll
      for (int j = 0; j < FJ; ++j)
        acc[i][j] = __builtin_amdgcn_mfma_f32_16x16x32_bf16(a[i], b[j], acc[i][j], 0, 0, 0);
    __syncthreads();
  }

  #pragma unroll
  for (int i = 0; i < FI; ++i) {
    #pragma unroll
    for (int j = 0; j < FJ; ++j) {
      int col = bn + wc*64 + j*16 + lr;
      #pragma unroll
      for (int q = 0; q < 4; ++q) {
        int row = bm + wr*64 + i*16 + lk*4 + q;
        if (row < M) Cb[(size_t)row*ldc + col] = f2bf(acc[i][j][q]);
      }
    }
  }
}

// ---------------- GATv2 attention: one wave per dst, 8-wide, NO online max ----------------
// xlr [R][NN][512]: cols 0-255 xl, 256-511 xr. lane l: head l>>4, ch 4*(l&15)..+3.
// Safety: logits bounded by data/weight scale (|p| << 100); fminf(p,100) guards exp2 overflow;
// self-loop term keeps s > 0.
__global__ __launch_bounds__(256) void k_gat(
    const u16* __restrict__ xlr,
    const float* __restrict__ att, const float* __restrict__ bias,
    const int* __restrict__ off4, const int* __restrict__ csr4,
    u16* __restrict__ out)
{
  const int z = blockIdx.z;
  int node = blockIdx.x*4 + (threadIdx.x >> 6);
  if (node >= NN) return;
  int lane = threadIdx.x & 63;
  const u16* xbase = xlr + (size_t)z*(size_t)NN*512;
  const int* off = off4 + (size_t)z*(NN+1);
  const int* csr = csr4 + (size_t)z*EE;
  u16* outp = out + (size_t)z*(size_t)NN*256;

  const size_t co = (size_t)lane*4;
  const u16* selfrow = xbase + (size_t)node*512;
  ushort4 xr4 = *reinterpret_cast<const ushort4*>(selfrow + 256 + co);
  const float xr0 = bf2f(xr4.x), xr1 = bf2f(xr4.y), xr2 = bf2f(xr4.z), xr3 = bf2f(xr4.w);
  float4 av = *reinterpret_cast<const float4*>(att + (size_t)z*256 + lane*4);
  const float L2E = 1.4426950408889634f;   // exp(e) == exp2(e*log2(e)); fold into att
  av.x *= L2E; av.y *= L2E; av.z *= L2E; av.w *= L2E;

  // self loop
  ushort4 xs = *reinterpret_cast<const ushort4*>(selfrow + co);
  float s0c = bf2f(xs.x), s1c = bf2f(xs.y), s2c = bf2f(xs.z), s3c = bf2f(xs.w);
  float ps = av.x*lrelu(s0c+xr0) + av.y*lrelu(s1c+xr1) + av.z*lrelu(s2c+xr2) + av.w*lrelu(s3c+xr3);
  ps += __shfl_xor(ps, 1);
  ps += __shfl_xor(ps, 2);
  ps += __shfl_xor(ps, 4);
  ps += __shfl_xor(ps, 8);
  float wsf = exp2f(fminf(ps, 100.f));
  float s = wsf;
  float a0 = wsf*s0c, a1 = wsf*s1c, a2 = wsf*s2c, a3 = wsf*s3c;

  const int e0 = off[node], e1 = off[node+1];
  const int e1m1 = e1 - 1;
  for (int k = e0; k < e1; k += 8) {
    float xv[8][4], p[8];
    #pragma unroll
    for (int j = 0; j < 8; ++j) {
      int kk = k + j;
      int idx = csr[kk < e1 ? kk : e1m1];
      ushort4 v = *reinterpret_cast<const ushort4*>(xbase + (size_t)idx*512 + co);
      xv[j][0] = bf2f(v.x); xv[j][1] = bf2f(v.y); xv[j][2] = bf2f(v.z); xv[j][3] = bf2f(v.w);
      p[j] = av.x*lrelu(xv[j][0]+xr0) + av.y*lrelu(xv[j][1]+xr1)
           + av.z*lrelu(xv[j][2]+xr2) + av.w*lrelu(xv[j][3]+xr3);
    }
    #pragma unroll
    for (int j = 0; j < 8; ++j) p[j] += __shfl_xor(p[j], 1);
    #pragma unroll
    for (int j = 0; j < 8; ++j) p[j] += __shfl_xor(p[j], 2);
    #pragma unroll
    for (int j = 0; j < 8; ++j) p[j] += __shfl_xor(p[j], 4);
    #pragma unroll
    for (int j = 0; j < 8; ++j) p[j] += __shfl_xor(p[j], 8);
    float w[8];
    #pragma unroll
    for (int j = 0; j < 8; ++j) {
      float e = exp2f(fminf(p[j], 100.f));
      w[j] = (k + j < e1) ? e : 0.f;
    }
    s += ((w[0]+w[1])+(w[2]+w[3])) + ((w[4]+w[5])+(w[6]+w[7]));
    #pragma unroll
    for (int j = 0; j < 8; ++j) {
      a0 += w[j]*xv[j][0]; a1 += w[j]*xv[j][1];
      a2 += w[j]*xv[j][2]; a3 += w[j]*xv[j][3];
    }
  }
  float inv = 1.f / s;
  const float4 bv = *reinterpret_cast<const float4*>(bias + (size_t)z*256 + lane*4);
  ushort4 o;
  o.x = f2bf(fmaxf(a0*inv + bv.x, 0.f));   // both GAT layers followed by ReLU
  o.y = f2bf(fmaxf(a1*inv + bv.y, 0.f));
  o.z = f2bf(fmaxf(a2*inv + bv.z, 0.f));
  o.w = f2bf(fmaxf(a3*inv + bv.w, 0.f));
  *reinterpret_cast<ushort4*>(outp + (size_t)node*256 + co) = o;
}

// ---------------- GraphConv: aggregate projected P-slice + fused epilogue ----------------
// C [R][NN][128] = [P|Q] where P = h@Wrel, Q = h@Wroot.
// result = act(sum_{j in N(i)} P[j] + Q[i] + bias)  -> bf16 [R][NN][64] or f32 out[:,z,:].
template<int RELU, int F32OUT>
__global__ __launch_bounds__(256) void k_aggp(
    const u16* __restrict__ C, const float* __restrict__ bias,
    const int* __restrict__ off4, const int* __restrict__ csr4,
    u16* __restrict__ outb, float* __restrict__ outf)
{
  const int z = blockIdx.z;
  int node = blockIdx.x*4 + (threadIdx.x >> 6);
  if (node >= NN) return;
  int lane = threadIdx.x & 63;
  const u16* Cp = C + (size_t)z*(size_t)NN*128;
  const int* off = off4 + (size_t)z*(NN+1);
  const int* csr = csr4 + (size_t)z*EE;
  float a = 0.f;
  const int e0 = off[node], e1 = off[node+1];
  const int e1m1 = e1 - 1;
  for (int k = e0; k < e1; k += 8) {
    #pragma unroll
    for (int j = 0; j < 8; ++j) {
      int kk = k + j;
      int idx = csr[kk < e1 ? kk : e1m1];
      float v = bf2f(Cp[(size_t)idx*128 + lane]);
      a += (kk < e1) ? v : 0.f;
    }
  }
  float q = bf2f(Cp[(size_t)node*128 + 64 + lane]);
  float v = a + q + bias[z*64 + lane];
  if (RELU) v = fmaxf(v, 0.f);
  if (F32OUT) outf[(size_t)node*256 + z*64 + lane] = v;
  else        outb[((size_t)z*NN + node)*64 + lane] = f2bf(v);
}

// ---------------- orchestration ----------------
extern "C" void kernel_launch(void* const* d_in, const int* in_sizes, int n_in,
                              void* d_out, int out_size, void* d_ws, size_t ws_size,
                              hipStream_t stream)
{
  const float* x      = (const float*)d_in[0];
  const int*   ei     = (const int*)  d_in[1];
  const float* Wl1    = (const float*)d_in[2];
  const float* Wr1    = (const float*)d_in[3];
  const float* att1   = (const float*)d_in[4];
  const float* b1     = (const float*)d_in[5];
  const float* Wl2    = (const float*)d_in[6];
  const float* Wr2    = (const float*)d_in[7];
  const float* att2   = (const float*)d_in[8];
  const float* b2     = (const float*)d_in[9];
  const float* Wrel3  = (const float*)d_in[10];
  const float* Wroot3 = (const float*)d_in[11];
  const float* b3     = (const float*)d_in[12];
  const float* Wrel4  = (const float*)d_in[13];
  const float* Wroot4 = (const float*)d_in[14];
  const float* b4     = (const float*)d_in[15];
  float* out = (float*)d_out;

  const dim3 thr(256);
  const size_t NB512 = (size_t)NN*512;
  const size_t NB256 = (size_t)NN*256;
  const size_t NB128 = (size_t)NN*128;
  const size_t NB64  = (size_t)NN*64;

  // workspace (u16 units). C34/h3b alias XLR (free after gat2).
  u16* XLR = (u16*)d_ws;                          // [R][NN][512]  (81.9 MB)
  u16* h   = XLR + NB512*RR;                      // [R][NN][256]  (41 MB)
  u16* xbf = h   + NB256*RR;                      // [NN][256]
  u16* W1T = xbf + NB256;                         // [R][512][256]
  u16* W2T = W1T + (size_t)RR*512*256;
  u16* W3T = W2T + (size_t)RR*512*256;            // [R][128][256]
  u16* W4T = W3T + (size_t)RR*128*256;            // [R][128][64]
  int* deg4 = (int*)(W4T + (size_t)RR*128*64);
  int* off4 = deg4 + RR*NN;
  int* cur4 = off4 + RR*(NN+1);
  int* csr4 = cur4 + RR*NN;                       // R*EE
  u16* C34 = XLR;                                 // [R][NN][128] aliases XLR
  u16* h3b = XLR + NB128*RR;                      // [R][NN][64]  aliases XLR (disjoint region)

  // prep
  k_cast<<<dim3((NN*256/4+255)/256), thr, 0, stream>>>(x, xbf, NN*256/4);
  k_prep<<<dim3((RR*512*256+255)/256), thr, 0, stream>>>(Wl1, Wr1, W1T, 256, 256, RR*512*256);
  k_prep<<<dim3((RR*512*256+255)/256), thr, 0, stream>>>(Wl2, Wr2, W2T, 256, 256, RR*512*256);
  k_prep<<<dim3((RR*128*256+255)/256), thr, 0, stream>>>(Wrel3, Wroot3, W3T, 256, 64, RR*128*256);
  k_prep<<<dim3((RR*128*64+255)/256),  thr, 0, stream>>>(Wrel4, Wroot4, W4T, 64, 64, RR*128*64);

  // CSR
  k_zero_int<<<dim3((RR*NN+255)/256), thr, 0, stream>>>(deg4, RR*NN);
  k_countA  <<<dim3((RR*EE+255)/256), thr, 0, stream>>>(ei, deg4);
  k_scan    <<<dim3(RR), dim3(1024), 0, stream>>>(deg4, off4, cur4, NN);
  for (int p = 0; p < 4; ++p)
    k_scatter4<<<dim3((RR*EE+255)/256), thr, 0, stream>>>(ei, cur4, csr4, p*5000, (p+1)*5000);

  const dim3 gNode(5000, 1, RR);
  // L1: XLR[z] = xbf @ [Wl1|Wr1][z]
  k_mfma<<<dim3(157,4,RR), thr, 0, stream>>>(xbf, W1T, NN, 256, XLR, 512,
                                             0, 512*256, (long)NB512);
  k_gat<<<gNode, thr, 0, stream>>>(XLR, att1, b1, off4, csr4, h);
  // L2
  k_mfma<<<dim3(157,4,RR), thr, 0, stream>>>(h, W2T, NN, 256, XLR, 512,
                                             (long)NB256, 512*256, (long)NB512);
  k_gat<<<gNode, thr, 0, stream>>>(XLR, att2, b2, off4, csr4, h);
  // L3: C34[z] = h[z] @ [Wrel3|Wroot3][z] ; h3 = relu(aggP + Q + b3)
  k_mfma<<<dim3(157,1,RR), thr, 0, stream>>>(h, W3T, NN, 256, C34, 128,
                                             (long)NB256, 128*256, (long)NB128);
  k_aggp<1,0><<<gNode, thr, 0, stream>>>(C34, b3, off4, csr4, h3b, nullptr);
  // L4: C34[z] = h3[z] @ [Wrel4|Wroot4][z] ; out[:,z,:] = aggP + Q + b4
  k_mfma<<<dim3(157,1,RR), thr, 0, stream>>>(h3b, W4T, NN, 64, C34, 128,
                                             (long)NB64, 128*64, (long)NB128);
  k_aggp<0,1><<<gNode, thr, 0, stream>>>(C34, b4, off4, csr4, nullptr, out);
}

// Round 6
// 671.830 us; speedup vs baseline: 1.3726x; 1.0402x over previous
//
#include <hip/hip_runtime.h>
#include <math.h>

#define NN   20000
#define EE   320000
#define RR   4

typedef unsigned short u16;
typedef unsigned int   u32;
typedef __attribute__((ext_vector_type(8))) short short8v;   // 8 bf16 (4 VGPRs)
typedef __attribute__((ext_vector_type(4))) float f32x4;

static __device__ __forceinline__ float lrelu(float v){ return fmaxf(v, 0.2f*v); }
static __device__ __forceinline__ float bf2f(u16 u){ return __uint_as_float(((u32)u) << 16); }
static __device__ __forceinline__ float bflo(u32 u){ return __uint_as_float(u << 16); }
static __device__ __forceinline__ float bfhi(u32 u){ return __uint_as_float(u & 0xffff0000u); }
static __device__ __forceinline__ u16 f2bf(float f){
  u32 u = __float_as_uint(f);
  u += 0x7fff + ((u >> 16) & 1);        // round-to-nearest-even
  return (u16)(u >> 16);
}
static __device__ __forceinline__ void gload_lds16(const void* g, void* l){
  __builtin_amdgcn_global_load_lds((const __attribute__((address_space(1))) void*)g,
                                   (__attribute__((address_space(3))) void*)l, 16, 0, 0);
}

// ---------------- CSR build ----------------
__global__ void k_zero_int(int* __restrict__ p, int n){
  int i = blockIdx.x*blockDim.x + threadIdx.x;
  if (i < n) p[i] = 0;
}
__global__ void k_countA(const int* __restrict__ ei, int* __restrict__ deg4){
  int i = blockIdx.x*blockDim.x + threadIdx.x;
  if (i < RR*EE) {
    int r = i / EE, e = i % EE;
    int d = ei[(size_t)r*2*EE + EE + e];
    atomicAdd(&deg4[r*NN + d], 1);
  }
}
__global__ __launch_bounds__(1024) void k_scan(const int* __restrict__ cnt_all, int* __restrict__ off_all,
                                               int* __restrict__ cur_all, int n){
  const int* cnt = cnt_all + (size_t)blockIdx.x*n;
  int* off = off_all + (size_t)blockIdx.x*(n+1);
  int* cur = cur_all + (size_t)blockIdx.x*n;
  __shared__ int part[1024];
  int t = threadIdx.x;
  int chunk = (n + 1023) >> 10;
  int lo = t*chunk; if (lo > n) lo = n;
  int hi = lo + chunk; if (hi > n) hi = n;
  int s = 0;
  for (int i = lo; i < hi; ++i) s += cnt[i];
  part[t] = s;
  __syncthreads();
  for (int d = 1; d < 1024; d <<= 1) {
    int u = (t >= d) ? part[t-d] : 0;
    __syncthreads();
    part[t] += u;
    __syncthreads();
  }
  int run = (t == 0) ? 0 : part[t-1];
  for (int i = lo; i < hi; ++i) { off[i] = run; cur[i] = run; run += cnt[i]; }
  if (t == 1023) off[n] = part[1023];
}
// scatter: 4 dst-range passes keep the random 4B writes L2-local
__global__ void k_scatter4(const int* __restrict__ ei, int* __restrict__ cur4, int* __restrict__ csr4,
                           int dlo, int dhi){
  int i = blockIdx.x*blockDim.x + threadIdx.x;
  if (i < RR*EE) {
    int r = i / EE, e = i % EE;
    int d = ei[(size_t)r*2*EE + EE + e];
    if (d >= dlo && d < dhi) {
      int s = ei[(size_t)r*2*EE + e];
      int p = atomicAdd(&cur4[r*NN + d], 1);
      csr4[(size_t)r*EE + p] = s;
    }
  }
}

// ---------------- prep ----------------
__global__ void k_cast(const float* __restrict__ x, u16* __restrict__ o, int n4){
  int i = blockIdx.x*blockDim.x + threadIdx.x;
  if (i < n4) {
    float4 v = reinterpret_cast<const float4*>(x)[i];
    ushort4 b;
    b.x = f2bf(v.x); b.y = f2bf(v.y); b.z = f2bf(v.z); b.w = f2bf(v.w);
    reinterpret_cast<ushort4*>(o)[i] = b;
  }
}
// dst[r][n][k] bf16 with n in [0,2N): n<N from A (=A^T), else from B. src f32 [r][K][N].
__global__ void k_prep(const float* __restrict__ A, const float* __restrict__ B,
                       u16* __restrict__ dst, int K, int N, int total){
  int i = blockIdx.x*blockDim.x + threadIdx.x;
  if (i >= total) return;
  int k = i % K;
  int n = (i / K) % (2*N);
  int r = i / (K*2*N);
  const float* S = (n < N) ? A : B;
  int nn = (n < N) ? n : n - N;
  dst[i] = f2bf(S[((size_t)r*K + k)*N + nn]);
}

// ---------------- MFMA GEMM: Cb = A@BT^T (bf16 out); z-batched ----------------
__global__ __launch_bounds__(256) void k_mfma(
    const u16* __restrict__ A, const u16* __restrict__ BT,
    int M, int K, u16* __restrict__ Cb, int ldc,
    long aZ, long btZ, long cZ)
{
  constexpr int BM = 128, BN = 128;
  constexpr int FI = 4, FJ = 4;
  const int zz = blockIdx.z;
  A  += (size_t)zz*aZ;
  BT += (size_t)zz*btZ;
  Cb += (size_t)zz*cZ;

  __shared__ u16 As[BM*32];
  __shared__ u16 Bs[BN*32];
  const int t = threadIdx.x;
  const int lane = t & 63, wid = t >> 6;
  const int wr = wid >> 1, wc = wid & 1;
  const int bm = blockIdx.x * BM, bn = blockIdx.y * BN;
  const int lr = lane & 15, lk = lane >> 4;

  f32x4 acc[FI][FJ];
  #pragma unroll
  for (int i = 0; i < FI; ++i)
    #pragma unroll
    for (int j = 0; j < FJ; ++j) acc[i][j] = (f32x4)(0.f);

  const int nk = K >> 5;
  char* AsB = (char*)As;
  char* BsB = (char*)Bs;

  for (int s = 0; s < nk; ++s) {
    const int kk = s << 5;
    #pragma unroll
    for (int i = 0; i < 2; ++i) {
      int c = t + 256*i;
      int row = c >> 2, sub = c & 3;
      int lsub = sub ^ (row & 3);
      int grow = bm + row; if (grow >= M) grow = M - 1;
      gload_lds16(A + (size_t)grow*K + kk + lsub*8, AsB + c*16);
    }
    #pragma unroll
    for (int i = 0; i < 2; ++i) {
      int c = t + 256*i;
      int row = c >> 2, sub = c & 3;
      int lsub = sub ^ (row & 3);
      gload_lds16(BT + (size_t)(bn + row)*K + kk + lsub*8, BsB + c*16);
    }
    __syncthreads();
    short8v a[FI], b[FJ];
    #pragma unroll
    for (int i = 0; i < FI; ++i) {
      int row = wr*64 + i*16 + lr;
      int sub = lk ^ (row & 3);
      a[i] = *reinterpret_cast<short8v*>(AsB + row*64 + sub*16);
    }
    #pragma unroll
    for (int j = 0; j < FJ; ++j) {
      int col = wc*64 + j*16 + lr;
      int sub = lk ^ (col & 3);
      b[j] = *reinterpret_cast<short8v*>(BsB + col*64 + sub*16);
    }
    #pragma unroll
    for (int i = 0; i < FI; ++i)
      #pragma unroll
      for (int j = 0; j < FJ; ++j)
        acc[i][j] = __builtin_amdgcn_mfma_f32_16x16x32_bf16(a[i], b[j], acc[i][j], 0, 0, 0);
    __syncthreads();
  }

  #pragma unroll
  for (int i = 0; i < FI; ++i) {
    #pragma unroll
    for (int j = 0; j < FJ; ++j) {
      int col = bn + wc*64 + j*16 + lr;
      #pragma unroll
      for (int q = 0; q < 4; ++q) {
        int row = bm + wr*64 + i*16 + lk*4 + q;
        if (row < M) Cb[(size_t)row*ldc + col] = f2bf(acc[i][j][q]);
      }
    }
  }
}

// ---------------- GATv2 attention: one wave per dst, 8 ch/lane, 2 edges/wave ----------------
// xlr [R][NN][512]: cols 0-255 xl, 256-511 xr. Sub-wave sub=lane>>5 handles edges k+2j+sub.
// Lane covers channels (lane&31)*8 .. +7; head = (lane&31)>>3; head-dot reduce = shfl 1,2,4.
__global__ __launch_bounds__(256) void k_gat(
    const u16* __restrict__ xlr,
    const float* __restrict__ att, const float* __restrict__ bias,
    const int* __restrict__ off4, const int* __restrict__ csr4,
    u16* __restrict__ out)
{
  const int z = blockIdx.z;
  int node = blockIdx.x*4 + (threadIdx.x >> 6);
  if (node >= NN) return;
  const int lane = threadIdx.x & 63;
  const int sl = lane & 31, sub = lane >> 5;
  const u16* xbase = xlr + (size_t)z*(size_t)NN*512;
  const int* off = off4 + (size_t)z*(NN+1);
  const int* csr = csr4 + (size_t)z*EE;
  u16* outp = out + (size_t)z*(size_t)NN*256;

  const int co = sl*8;                           // channel offset in 256
  const u16* selfrow = xbase + (size_t)node*512;
  uint4 rx = *reinterpret_cast<const uint4*>(selfrow + 256 + co);
  float xr[8] = {bflo(rx.x),bfhi(rx.x),bflo(rx.y),bfhi(rx.y),
                 bflo(rx.z),bfhi(rx.z),bflo(rx.w),bfhi(rx.w)};
  const float L2E = 1.4426950408889634f;
  float av[8];
  {
    float4 q0 = *reinterpret_cast<const float4*>(att + z*256 + co);
    float4 q1 = *reinterpret_cast<const float4*>(att + z*256 + co + 4);
    av[0]=q0.x*L2E; av[1]=q0.y*L2E; av[2]=q0.z*L2E; av[3]=q0.w*L2E;
    av[4]=q1.x*L2E; av[5]=q1.y*L2E; av[6]=q1.z*L2E; av[7]=q1.w*L2E;
  }
  // self loop (counted once: sub0 only)
  uint4 sx = *reinterpret_cast<const uint4*>(selfrow + co);
  float xs[8] = {bflo(sx.x),bfhi(sx.x),bflo(sx.y),bfhi(sx.y),
                 bflo(sx.z),bfhi(sx.z),bflo(sx.w),bfhi(sx.w)};
  float ps = 0.f;
  #pragma unroll
  for (int i = 0; i < 8; ++i) ps += av[i]*lrelu(xs[i]+xr[i]);
  ps += __shfl_xor(ps,1); ps += __shfl_xor(ps,2); ps += __shfl_xor(ps,4);
  float wsf = (sub == 0) ? exp2f(fminf(ps,100.f)) : 0.f;
  float s = wsf;
  float a[8];
  #pragma unroll
  for (int i = 0; i < 8; ++i) a[i] = wsf*xs[i];

  const int e0 = off[node], e1 = off[node+1];
  const int e1m1 = e1 - 1;
  for (int k = e0; k < e1; k += 4) {             // 4 edges/iter: 2 per sub
    float xv[2][8], p[2];
    int kks[2];
    #pragma unroll
    for (int j = 0; j < 2; ++j) {
      int kk = k + 2*j + sub;
      kks[j] = kk;
      int idx = csr[kk <= e1m1 ? kk : e1m1];
      uint4 v = *reinterpret_cast<const uint4*>(xbase + (size_t)idx*512 + co);
      xv[j][0]=bflo(v.x); xv[j][1]=bfhi(v.x); xv[j][2]=bflo(v.y); xv[j][3]=bfhi(v.y);
      xv[j][4]=bflo(v.z); xv[j][5]=bfhi(v.z); xv[j][6]=bflo(v.w); xv[j][7]=bfhi(v.w);
      float pp = 0.f;
      #pragma unroll
      for (int i = 0; i < 8; ++i) pp += av[i]*lrelu(xv[j][i]+xr[i]);
      p[j] = pp;
    }
    #pragma unroll
    for (int j = 0; j < 2; ++j) {
      p[j] += __shfl_xor(p[j],1);
      p[j] += __shfl_xor(p[j],2);
      p[j] += __shfl_xor(p[j],4);
    }
    float w[2];
    #pragma unroll
    for (int j = 0; j < 2; ++j)
      w[j] = (kks[j] < e1) ? exp2f(fminf(p[j],100.f)) : 0.f;
    s += w[0] + w[1];
    #pragma unroll
    for (int i = 0; i < 8; ++i) a[i] += w[0]*xv[0][i] + w[1]*xv[1][i];
  }
  // combine sub-waves (lane l <-> l+32 have same head/channels)
  s += __shfl_xor(s, 32);
  #pragma unroll
  for (int i = 0; i < 8; ++i) a[i] += __shfl_xor(a[i], 32);
  float inv = 1.f / s;
  float4 b0 = *reinterpret_cast<const float4*>(bias + z*256 + co);
  float4 b1 = *reinterpret_cast<const float4*>(bias + z*256 + co + 4);
  float bv[8] = {b0.x,b0.y,b0.z,b0.w,b1.x,b1.y,b1.z,b1.w};
  u32 o[4];
  #pragma unroll
  for (int i = 0; i < 4; ++i) {
    u16 lo = f2bf(fmaxf(a[2*i]*inv   + bv[2*i],   0.f));
    u16 hi = f2bf(fmaxf(a[2*i+1]*inv + bv[2*i+1], 0.f));
    o[i] = (u32)lo | ((u32)hi << 16);
  }
  if (sub == 0) {
    uint4 ov = {o[0], o[1], o[2], o[3]};
    *reinterpret_cast<uint4*>(outp + (size_t)node*256 + co) = ov;
  }
}

// ---------------- GraphConv: aggregate projected P-slice; 2 ch/lane, 2 edges/wave ----------------
// C [R][NN][128] = [P|Q]; result = act(sum_j P[j] + Q[i] + bias).
template<int RELU, int F32OUT>
__global__ __launch_bounds__(256) void k_aggp(
    const u16* __restrict__ C, const float* __restrict__ bias,
    const int* __restrict__ off4, const int* __restrict__ csr4,
    u16* __restrict__ outb, float* __restrict__ outf)
{
  const int z = blockIdx.z;
  int node = blockIdx.x*4 + (threadIdx.x >> 6);
  if (node >= NN) return;
  const int lane = threadIdx.x & 63;
  const int sl = lane & 31, sub = lane >> 5;
  const u16* Cp = C + (size_t)z*(size_t)NN*128;
  const int* off = off4 + (size_t)z*(NN+1);
  const int* csr = csr4 + (size_t)z*EE;
  const int co = sl*2;
  float alo = 0.f, ahi = 0.f;
  const int e0 = off[node], e1 = off[node+1];
  const int e1m1 = e1 - 1;
  for (int k = e0; k < e1; k += 4) {
    #pragma unroll
    for (int j = 0; j < 2; ++j) {
      int kk = k + 2*j + sub;
      int idx = csr[kk <= e1m1 ? kk : e1m1];
      u32 v = *reinterpret_cast<const u32*>(Cp + (size_t)idx*128 + co);
      bool val = kk < e1;
      alo += val ? bflo(v) : 0.f;
      ahi += val ? bfhi(v) : 0.f;
    }
  }
  alo += __shfl_xor(alo, 32);
  ahi += __shfl_xor(ahi, 32);
  if (sub == 0) {
    u32 q = *reinterpret_cast<const u32*>(Cp + (size_t)node*128 + 64 + co);
    float2 bv = *reinterpret_cast<const float2*>(bias + z*64 + co);
    float vlo = alo + bflo(q) + bv.x;
    float vhi = ahi + bfhi(q) + bv.y;
    if (RELU) { vlo = fmaxf(vlo, 0.f); vhi = fmaxf(vhi, 0.f); }
    if (F32OUT) {
      float2 o = {vlo, vhi};
      *reinterpret_cast<float2*>(outf + (size_t)node*256 + z*64 + co) = o;
    } else {
      u32 o = (u32)f2bf(vlo) | ((u32)f2bf(vhi) << 16);
      *reinterpret_cast<u32*>(outb + ((size_t)z*NN + node)*64 + co) = o;
    }
  }
}

// ---------------- orchestration ----------------
extern "C" void kernel_launch(void* const* d_in, const int* in_sizes, int n_in,
                              void* d_out, int out_size, void* d_ws, size_t ws_size,
                              hipStream_t stream)
{
  const float* x      = (const float*)d_in[0];
  const int*   ei     = (const int*)  d_in[1];
  const float* Wl1    = (const float*)d_in[2];
  const float* Wr1    = (const float*)d_in[3];
  const float* att1   = (const float*)d_in[4];
  const float* b1     = (const float*)d_in[5];
  const float* Wl2    = (const float*)d_in[6];
  const float* Wr2    = (const float*)d_in[7];
  const float* att2   = (const float*)d_in[8];
  const float* b2     = (const float*)d_in[9];
  const float* Wrel3  = (const float*)d_in[10];
  const float* Wroot3 = (const float*)d_in[11];
  const float* b3     = (const float*)d_in[12];
  const float* Wrel4  = (const float*)d_in[13];
  const float* Wroot4 = (const float*)d_in[14];
  const float* b4     = (const float*)d_in[15];
  float* out = (float*)d_out;

  const dim3 thr(256);
  const size_t NB512 = (size_t)NN*512;
  const size_t NB256 = (size_t)NN*256;
  const size_t NB128 = (size_t)NN*128;
  const size_t NB64  = (size_t)NN*64;

  u16* XLR = (u16*)d_ws;                          // [R][NN][512]
  u16* h   = XLR + NB512*RR;                      // [R][NN][256]
  u16* xbf = h   + NB256*RR;                      // [NN][256]
  u16* W1T = xbf + NB256;                         // [R][512][256]
  u16* W2T = W1T + (size_t)RR*512*256;
  u16* W3T = W2T + (size_t)RR*512*256;            // [R][128][256]
  u16* W4T = W3T + (size_t)RR*128*256;            // [R][128][64]
  int* deg4 = (int*)(W4T + (size_t)RR*128*64);
  int* off4 = deg4 + RR*NN;
  int* cur4 = off4 + RR*(NN+1);
  int* csr4 = cur4 + RR*NN;                       // R*EE
  u16* C34 = XLR;                                 // [R][NN][128] aliases XLR
  u16* h3b = XLR + NB128*RR;                      // [R][NN][64]  aliases XLR (disjoint)

  // prep
  k_cast<<<dim3((NN*256/4+255)/256), thr, 0, stream>>>(x, xbf, NN*256/4);
  k_prep<<<dim3((RR*512*256+255)/256), thr, 0, stream>>>(Wl1, Wr1, W1T, 256, 256, RR*512*256);
  k_prep<<<dim3((RR*512*256+255)/256), thr, 0, stream>>>(Wl2, Wr2, W2T, 256, 256, RR*512*256);
  k_prep<<<dim3((RR*128*256+255)/256), thr, 0, stream>>>(Wrel3, Wroot3, W3T, 256, 64, RR*128*256);
  k_prep<<<dim3((RR*128*64+255)/256),  thr, 0, stream>>>(Wrel4, Wroot4, W4T, 64, 64, RR*128*64);

  // CSR
  k_zero_int<<<dim3((RR*NN+255)/256), thr, 0, stream>>>(deg4, RR*NN);
  k_countA  <<<dim3((RR*EE+255)/256), thr, 0, stream>>>(ei, deg4);
  k_scan    <<<dim3(RR), dim3(1024), 0, stream>>>(deg4, off4, cur4, NN);
  for (int p = 0; p < 4; ++p)
    k_scatter4<<<dim3((RR*EE+255)/256), thr, 0, stream>>>(ei, cur4, csr4, p*5000, (p+1)*5000);

  const dim3 gNode(5000, 1, RR);
  // L1: XLR[z] = xbf @ [Wl1|Wr1][z]
  k_mfma<<<dim3(157,4,RR), thr, 0, stream>>>(xbf, W1T, NN, 256, XLR, 512,
                                             0, 512*256, (long)NB512);
  k_gat<<<gNode, thr, 0, stream>>>(XLR, att1, b1, off4, csr4, h);
  // L2
  k_mfma<<<dim3(157,4,RR), thr, 0, stream>>>(h, W2T, NN, 256, XLR, 512,
                                             (long)NB256, 512*256, (long)NB512);
  k_gat<<<gNode, thr, 0, stream>>>(XLR, att2, b2, off4, csr4, h);
  // L3: C34[z] = h[z] @ [Wrel3|Wroot3][z] ; h3 = relu(aggP + Q + b3)
  k_mfma<<<dim3(157,1,RR), thr, 0, stream>>>(h, W3T, NN, 256, C34, 128,
                                             (long)NB256, 128*256, (long)NB128);
  k_aggp<1,0><<<gNode, thr, 0, stream>>>(C34, b3, off4, csr4, h3b, nullptr);
  // L4: C34[z] = h3[z] @ [Wrel4|Wroot4][z] ; out[:,z,:] = aggP + Q + b4
  k_mfma<<<dim3(157,1,RR), thr, 0, stream>>>(h3b, W4T, NN, 64, C34, 128,
                                             (long)NB64, 128*64, (long)NB128);
  k_aggp<0,1><<<gNode, thr, 0, stream>>>(C34, b4, off4, csr4, nullptr, out);
}

// Round 8
// 602.822 us; speedup vs baseline: 1.5298x; 1.1145x over previous
//
#include <hip/hip_runtime.h>
#include <hip/hip_fp16.h>
#include <math.h>

#define NN   20000
#define EE   320000
#define RR   4

typedef unsigned short u16;
typedef unsigned int   u32;
typedef _Float16 half8v __attribute__((ext_vector_type(8)));
typedef _Float16 v2h    __attribute__((ext_vector_type(2)));
typedef __attribute__((ext_vector_type(4))) float f32x4;

static __device__ __forceinline__ u16 f2h(float f){ return __half_as_ushort(__float2half_rn(f)); }
static __device__ __forceinline__ v2h u2v(u32 u){ union{u32 u; v2h v;} c; c.u=u; return c.v; }
static __device__ __forceinline__ u32 v2u(v2h v){ union{u32 u; v2h v;} c; c.v=v; return c.u; }
static __device__ __forceinline__ v2h splat2(float f){ v2h r; r[0]=(_Float16)f; r[1]=(_Float16)f; return r; }
static __device__ __forceinline__ float fdot2(v2h a, v2h b, float c){
  return __builtin_amdgcn_fdot2(a, b, c, false);
}
static __device__ __forceinline__ void gload_lds16(const void* g, void* l){
  __builtin_amdgcn_global_load_lds((const __attribute__((address_space(1))) void*)g,
                                   (__attribute__((address_space(3))) void*)l, 16, 0, 0);
}

// ---------------- CSR build ----------------
__global__ void k_zero_int(int* __restrict__ p, int n){
  int i = blockIdx.x*blockDim.x + threadIdx.x;
  if (i < n) p[i] = 0;
}
__global__ void k_countA(const int* __restrict__ ei, int* __restrict__ deg4){
  int i = blockIdx.x*blockDim.x + threadIdx.x;
  if (i < RR*EE) {
    int r = i / EE, e = i % EE;
    int d = ei[(size_t)r*2*EE + EE + e];
    atomicAdd(&deg4[r*NN + d], 1);
  }
}
__global__ __launch_bounds__(1024) void k_scan(const int* __restrict__ cnt_all, int* __restrict__ off_all,
                                               int* __restrict__ cur_all, int n){
  const int* cnt = cnt_all + (size_t)blockIdx.x*n;
  int* off = off_all + (size_t)blockIdx.x*(n+1);
  int* cur = cur_all + (size_t)blockIdx.x*n;
  __shared__ int part[1024];
  int t = threadIdx.x;
  int chunk = (n + 1023) >> 10;
  int lo = t*chunk; if (lo > n) lo = n;
  int hi = lo + chunk; if (hi > n) hi = n;
  int s = 0;
  for (int i = lo; i < hi; ++i) s += cnt[i];
  part[t] = s;
  __syncthreads();
  for (int d = 1; d < 1024; d <<= 1) {
    int u = (t >= d) ? part[t-d] : 0;
    __syncthreads();
    part[t] += u;
    __syncthreads();
  }
  int run = (t == 0) ? 0 : part[t-1];
  for (int i = lo; i < hi; ++i) { off[i] = run; cur[i] = run; run += cnt[i]; }
  if (t == 1023) off[n] = part[1023];
}
// scatter: 4 dst-range passes keep the random 4B writes L2-local
__global__ void k_scatter4(const int* __restrict__ ei, int* __restrict__ cur4, int* __restrict__ csr4,
                           int dlo, int dhi){
  int i = blockIdx.x*blockDim.x + threadIdx.x;
  if (i < RR*EE) {
    int r = i / EE, e = i % EE;
    int d = ei[(size_t)r*2*EE + EE + e];
    if (d >= dlo && d < dhi) {
      int s = ei[(size_t)r*2*EE + e];
      int p = atomicAdd(&cur4[r*NN + d], 1);
      csr4[(size_t)r*EE + p] = s;
    }
  }
}

// ---------------- prep: f32 -> f16 cast / transposed-packed weights ----------------
__global__ void k_cast(const float* __restrict__ x, u16* __restrict__ o, int n4){
  int i = blockIdx.x*blockDim.x + threadIdx.x;
  if (i < n4) {
    float4 v = reinterpret_cast<const float4*>(x)[i];
    ushort4 b;
    b.x = f2h(v.x); b.y = f2h(v.y); b.z = f2h(v.z); b.w = f2h(v.w);
    reinterpret_cast<ushort4*>(o)[i] = b;
  }
}
// dst[r][n][k] f16 with n in [0,2N): n<N from A (=A^T), else from B. src f32 [r][K][N].
__global__ void k_prep(const float* __restrict__ A, const float* __restrict__ B,
                       u16* __restrict__ dst, int K, int N, int total){
  int i = blockIdx.x*blockDim.x + threadIdx.x;
  if (i >= total) return;
  int k = i % K;
  int n = (i / K) % (2*N);
  int r = i / (K*2*N);
  const float* S = (n < N) ? A : B;
  int nn = (n < N) ? n : n - N;
  dst[i] = f2h(S[((size_t)r*K + k)*N + nn]);
}

// ---------------- MFMA GEMM (f16): Cb = A@BT^T; z-batched ----------------
__global__ __launch_bounds__(256) void k_mfma(
    const u16* __restrict__ A, const u16* __restrict__ BT,
    int M, int K, u16* __restrict__ Cb, int ldc,
    long aZ, long btZ, long cZ)
{
  constexpr int BM = 128, BN = 128;
  constexpr int FI = 4, FJ = 4;
  const int zz = blockIdx.z;
  A  += (size_t)zz*aZ;
  BT += (size_t)zz*btZ;
  Cb += (size_t)zz*cZ;

  __shared__ u16 As[BM*32];
  __shared__ u16 Bs[BN*32];
  const int t = threadIdx.x;
  const int lane = t & 63, wid = t >> 6;
  const int wr = wid >> 1, wc = wid & 1;
  const int bm = blockIdx.x * BM, bn = blockIdx.y * BN;
  const int lr = lane & 15, lk = lane >> 4;

  f32x4 acc[FI][FJ];
  #pragma unroll
  for (int i = 0; i < FI; ++i)
    #pragma unroll
    for (int j = 0; j < FJ; ++j) acc[i][j] = (f32x4)(0.f);

  const int nk = K >> 5;
  char* AsB = (char*)As;
  char* BsB = (char*)Bs;

  for (int s = 0; s < nk; ++s) {
    const int kk = s << 5;
    #pragma unroll
    for (int i = 0; i < 2; ++i) {
      int c = t + 256*i;
      int row = c >> 2, sub = c & 3;
      int lsub = sub ^ (row & 3);
      int grow = bm + row; if (grow >= M) grow = M - 1;
      gload_lds16(A + (size_t)grow*K + kk + lsub*8, AsB + c*16);
    }
    #pragma unroll
    for (int i = 0; i < 2; ++i) {
      int c = t + 256*i;
      int row = c >> 2, sub = c & 3;
      int lsub = sub ^ (row & 3);
      gload_lds16(BT + (size_t)(bn + row)*K + kk + lsub*8, BsB + c*16);
    }
    __syncthreads();
    half8v a[FI], b[FJ];
    #pragma unroll
    for (int i = 0; i < FI; ++i) {
      int row = wr*64 + i*16 + lr;
      int sub = lk ^ (row & 3);
      a[i] = *reinterpret_cast<half8v*>(AsB + row*64 + sub*16);
    }
    #pragma unroll
    for (int j = 0; j < FJ; ++j) {
      int col = wc*64 + j*16 + lr;
      int sub = lk ^ (col & 3);
      b[j] = *reinterpret_cast<half8v*>(BsB + col*64 + sub*16);
    }
    #pragma unroll
    for (int i = 0; i < FI; ++i)
      #pragma unroll
      for (int j = 0; j < FJ; ++j)
        acc[i][j] = __builtin_amdgcn_mfma_f32_16x16x32_f16(a[i], b[j], acc[i][j], 0, 0, 0);
    __syncthreads();
  }

  #pragma unroll
  for (int i = 0; i < FI; ++i) {
    #pragma unroll
    for (int j = 0; j < FJ; ++j) {
      int col = bn + wc*64 + j*16 + lr;
      #pragma unroll
      for (int q = 0; q < 4; ++q) {
        int row = bm + wr*64 + i*16 + lk*4 + q;
        if (row < M) Cb[(size_t)row*ldc + col] = f2h(acc[i][j][q]);
      }
    }
  }
}

// ---------------- GATv2 attention: f16 packed, 8 ch/lane, 2 edges/wave ----------------
// xlr [NN][2048]: relation z occupies cols z*512..z*512+511 (0-255 xl, 256-511 xr).
// Weight scaling: w = exp2(p - 6) (power-of-2 scale cancels in a/s; keeps w in f16 range, cap 2^12).
__global__ __launch_bounds__(256) void k_gat(
    const u16* __restrict__ xlr,
    const float* __restrict__ att, const float* __restrict__ bias,
    const int* __restrict__ off4, const int* __restrict__ csr4,
    u16* __restrict__ out)
{
  const int z = blockIdx.z;
  int node = blockIdx.x*4 + (threadIdx.x >> 6);
  if (node >= NN) return;
  const int lane = threadIdx.x & 63;
  const int sl = lane & 31, sub = lane >> 5;
  const u16* xbase = xlr + (size_t)z*512;
  const int* off = off4 + (size_t)z*(NN+1);
  const int* csr = csr4 + (size_t)z*EE;
  u16* outp = out + (size_t)z*(size_t)NN*256;

  const int co = sl*8;
  const u16* selfrow = xbase + (size_t)node*2048;
  const v2h c02 = splat2(0.2f);
  const float L2E = 1.4426950408889634f;

  uint4 rx = *reinterpret_cast<const uint4*>(selfrow + 256 + co);
  v2h xr2[4] = {u2v(rx.x), u2v(rx.y), u2v(rx.z), u2v(rx.w)};
  v2h av2[4];
  {
    float4 q0 = *reinterpret_cast<const float4*>(att + z*256 + co);
    float4 q1 = *reinterpret_cast<const float4*>(att + z*256 + co + 4);
    av2[0][0]=(_Float16)(q0.x*L2E); av2[0][1]=(_Float16)(q0.y*L2E);
    av2[1][0]=(_Float16)(q0.z*L2E); av2[1][1]=(_Float16)(q0.w*L2E);
    av2[2][0]=(_Float16)(q1.x*L2E); av2[2][1]=(_Float16)(q1.y*L2E);
    av2[3][0]=(_Float16)(q1.z*L2E); av2[3][1]=(_Float16)(q1.w*L2E);
  }
  // self loop (sub 0 only)
  uint4 sx = *reinterpret_cast<const uint4*>(selfrow + co);
  v2h xs2[4] = {u2v(sx.x), u2v(sx.y), u2v(sx.z), u2v(sx.w)};
  float ps = 0.f;
  #pragma unroll
  for (int i = 0; i < 4; ++i) {
    v2h zz = xs2[i] + xr2[i];
    v2h lr = __builtin_elementwise_max(zz, zz*c02);
    ps = fdot2(av2[i], lr, ps);
  }
  ps += __shfl_xor(ps,1); ps += __shfl_xor(ps,2); ps += __shfl_xor(ps,4);
  float wsf = (sub == 0) ? exp2f(fminf(ps - 6.f, 12.f)) : 0.f;
  float s = wsf;
  v2h a2[4];
  {
    v2h w2 = splat2(wsf);
    #pragma unroll
    for (int i = 0; i < 4; ++i) a2[i] = w2*xs2[i];
  }

  const int e0 = off[node], e1 = off[node+1];
  const int e1m1 = e1 - 1;
  for (int k = e0; k < e1; k += 4) {             // 4 edges/iter: 2 per sub-half
    v2h xv[2][4];
    float p[2];
    int kks[2];
    #pragma unroll
    for (int j = 0; j < 2; ++j) {
      int kk = k + 2*j + sub;
      kks[j] = kk;
      int idx = csr[kk <= e1m1 ? kk : e1m1];
      uint4 v = *reinterpret_cast<const uint4*>(xbase + (size_t)idx*2048 + co);
      xv[j][0]=u2v(v.x); xv[j][1]=u2v(v.y); xv[j][2]=u2v(v.z); xv[j][3]=u2v(v.w);
      float pp = 0.f;
      #pragma unroll
      for (int i = 0; i < 4; ++i) {
        v2h zz = xv[j][i] + xr2[i];
        v2h lr = __builtin_elementwise_max(zz, zz*c02);
        pp = fdot2(av2[i], lr, pp);
      }
      p[j] = pp;
    }
    #pragma unroll
    for (int j = 0; j < 2; ++j) {
      p[j] += __shfl_xor(p[j],1);
      p[j] += __shfl_xor(p[j],2);
      p[j] += __shfl_xor(p[j],4);
    }
    float w0 = (kks[0] < e1) ? exp2f(fminf(p[0] - 6.f, 12.f)) : 0.f;
    float w1 = (kks[1] < e1) ? exp2f(fminf(p[1] - 6.f, 12.f)) : 0.f;
    s += w0 + w1;
    v2h w20 = splat2(w0), w21 = splat2(w1);
    #pragma unroll
    for (int i = 0; i < 4; ++i) {
      a2[i] += w20*xv[0][i];
      a2[i] += w21*xv[1][i];
    }
  }
  // combine sub-halves
  s += __shfl_xor(s, 32);
  #pragma unroll
  for (int i = 0; i < 4; ++i) {
    u32 t = (u32)__shfl_xor((int)v2u(a2[i]), 32);
    a2[i] += u2v(t);
  }
  float inv = 1.f / s;
  if (sub == 0) {
    float4 b0 = *reinterpret_cast<const float4*>(bias + z*256 + co);
    float4 b1 = *reinterpret_cast<const float4*>(bias + z*256 + co + 4);
    float bv[8] = {b0.x,b0.y,b0.z,b0.w,b1.x,b1.y,b1.z,b1.w};
    u32 o[4];
    #pragma unroll
    for (int i = 0; i < 4; ++i) {
      float lo = fmaxf((float)a2[i][0]*inv + bv[2*i],   0.f);
      float hi = fmaxf((float)a2[i][1]*inv + bv[2*i+1], 0.f);
      o[i] = (u32)f2h(lo) | ((u32)f2h(hi) << 16);
    }
    uint4 ov = {o[0], o[1], o[2], o[3]};
    *reinterpret_cast<uint4*>(outp + (size_t)node*256 + co) = ov;
  }
}

// ---------------- GraphConv: aggregate projected P-slice; 2 ch/lane, 2 edges/wave ----------------
// C [R][NN][128] f16 = [P|Q]; result = act(sum_j P[j] + Q[i] + bias).
template<int RELU, int F32OUT>
__global__ __launch_bounds__(256) void k_aggp(
    const u16* __restrict__ C, const float* __restrict__ bias,
    const int* __restrict__ off4, const int* __restrict__ csr4,
    u16* __restrict__ outb, float* __restrict__ outf)
{
  const int z = blockIdx.z;
  int node = blockIdx.x*4 + (threadIdx.x >> 6);
  if (node >= NN) return;
  const int lane = threadIdx.x & 63;
  const int sl = lane & 31, sub = lane >> 5;
  const u16* Cp = C + (size_t)z*(size_t)NN*128;
  const int* off = off4 + (size_t)z*(NN+1);
  const int* csr = csr4 + (size_t)z*EE;
  const int co = sl*2;
  float alo = 0.f, ahi = 0.f;
  const int e0 = off[node], e1 = off[node+1];
  const int e1m1 = e1 - 1;
  for (int k = e0; k < e1; k += 4) {
    #pragma unroll
    for (int j = 0; j < 2; ++j) {
      int kk = k + 2*j + sub;
      int idx = csr[kk <= e1m1 ? kk : e1m1];
      v2h v = u2v(*reinterpret_cast<const u32*>(Cp + (size_t)idx*128 + co));
      bool val = kk < e1;
      alo += val ? (float)v[0] : 0.f;
      ahi += val ? (float)v[1] : 0.f;
    }
  }
  alo += __shfl_xor(alo, 32);
  ahi += __shfl_xor(ahi, 32);
  if (sub == 0) {
    v2h q = u2v(*reinterpret_cast<const u32*>(Cp + (size_t)node*128 + 64 + co));
    float2 bv = *reinterpret_cast<const float2*>(bias + z*64 + co);
    float vlo = alo + (float)q[0] + bv.x;
    float vhi = ahi + (float)q[1] + bv.y;
    if (RELU) { vlo = fmaxf(vlo, 0.f); vhi = fmaxf(vhi, 0.f); }
    if (F32OUT) {
      float2 o = {vlo, vhi};
      *reinterpret_cast<float2*>(outf + (size_t)node*256 + z*64 + co) = o;
    } else {
      u32 o = (u32)f2h(vlo) | ((u32)f2h(vhi) << 16);
      *reinterpret_cast<u32*>(outb + ((size_t)z*NN + node)*64 + co) = o;
    }
  }
}

// ---------------- orchestration ----------------
extern "C" void kernel_launch(void* const* d_in, const int* in_sizes, int n_in,
                              void* d_out, int out_size, void* d_ws, size_t ws_size,
                              hipStream_t stream)
{
  const float* x      = (const float*)d_in[0];
  const int*   ei     = (const int*)  d_in[1];
  const float* Wl1    = (const float*)d_in[2];
  const float* Wr1    = (const float*)d_in[3];
  const float* att1   = (const float*)d_in[4];
  const float* b1     = (const float*)d_in[5];
  const float* Wl2    = (const float*)d_in[6];
  const float* Wr2    = (const float*)d_in[7];
  const float* att2   = (const float*)d_in[8];
  const float* b2     = (const float*)d_in[9];
  const float* Wrel3  = (const float*)d_in[10];
  const float* Wroot3 = (const float*)d_in[11];
  const float* b3     = (const float*)d_in[12];
  const float* Wrel4  = (const float*)d_in[13];
  const float* Wroot4 = (const float*)d_in[14];
  const float* b4     = (const float*)d_in[15];
  float* out = (float*)d_out;

  const dim3 thr(256);
  const size_t NB2048 = (size_t)NN*2048;
  const size_t NB256  = (size_t)NN*256;
  const size_t NB128  = (size_t)NN*128;
  const size_t NB64   = (size_t)NN*64;

  u16* XLR = (u16*)d_ws;                          // [NN][2048] (all relations side by side)
  u16* h   = XLR + NB2048;                        // [R][NN][256]
  u16* xbf = h   + NB256*RR;                      // [NN][256]
  u16* W1T = xbf + NB256;                         // [2048][256] (= [R][512][256])
  u16* W2T = W1T + (size_t)RR*512*256;
  u16* W3T = W2T + (size_t)RR*512*256;            // [R][128][256]
  u16* W4T = W3T + (size_t)RR*128*256;            // [R][128][64]
  int* deg4 = (int*)(W4T + (size_t)RR*128*64);
  int* off4 = deg4 + RR*NN;
  int* cur4 = off4 + RR*(NN+1);
  int* csr4 = cur4 + RR*NN;                       // R*EE
  u16* C34 = XLR;                                 // [R][NN][128] aliases XLR
  u16* h3b = XLR + NB128*RR;                      // [R][NN][64]  aliases XLR (disjoint)

  // prep
  k_cast<<<dim3((NN*256/4+255)/256), thr, 0, stream>>>(x, xbf, NN*256/4);
  k_prep<<<dim3((RR*512*256+255)/256), thr, 0, stream>>>(Wl1, Wr1, W1T, 256, 256, RR*512*256);
  k_prep<<<dim3((RR*512*256+255)/256), thr, 0, stream>>>(Wl2, Wr2, W2T, 256, 256, RR*512*256);
  k_prep<<<dim3((RR*128*256+255)/256), thr, 0, stream>>>(Wrel3, Wroot3, W3T, 256, 64, RR*128*256);
  k_prep<<<dim3((RR*128*64+255)/256),  thr, 0, stream>>>(Wrel4, Wroot4, W4T, 64, 64, RR*128*64);

  // CSR
  k_zero_int<<<dim3((RR*NN+255)/256), thr, 0, stream>>>(deg4, RR*NN);
  k_countA  <<<dim3((RR*EE+255)/256), thr, 0, stream>>>(ei, deg4);
  k_scan    <<<dim3(RR), dim3(1024), 0, stream>>>(deg4, off4, cur4, NN);
  for (int p = 0; p < 4; ++p)
    k_scatter4<<<dim3((RR*EE+255)/256), thr, 0, stream>>>(ei, cur4, csr4, p*5000, (p+1)*5000);

  const dim3 gNode(5000, 1, RR);
  // L1: XLR = xbf @ W1T^T  (single fused GEMM, N=2048)
  k_mfma<<<dim3(157,16,1), thr, 0, stream>>>(xbf, W1T, NN, 256, XLR, 2048, 0, 0, 0);
  k_gat<<<gNode, thr, 0, stream>>>(XLR, att1, b1, off4, csr4, h);
  // L2: per-z GEMM back into XLR column slices
  k_mfma<<<dim3(157,4,RR), thr, 0, stream>>>(h, W2T, NN, 256, XLR, 2048,
                                             (long)NB256, 512*256, 512);
  k_gat<<<gNode, thr, 0, stream>>>(XLR, att2, b2, off4, csr4, h);
  // L3: C34[z] = h[z] @ [Wrel3|Wroot3][z] ; h3 = relu(aggP + Q + b3)
  k_mfma<<<dim3(157,1,RR), thr, 0, stream>>>(h, W3T, NN, 256, C34, 128,
                                             (long)NB256, 128*256, (long)NB128);
  k_aggp<1,0><<<gNode, thr, 0, stream>>>(C34, b3, off4, csr4, h3b, nullptr);
  // L4: C34[z] = h3[z] @ [Wrel4|Wroot4][z] ; out[:,z,:] = aggP + Q + b4
  k_mfma<<<dim3(157,1,RR), thr, 0, stream>>>(h3b, W4T, NN, 64, C34, 128,
                                             (long)NB64, 128*64, (long)NB128);
  k_aggp<0,1><<<gNode, thr, 0, stream>>>(C34, b4, off4, csr4, nullptr, out);
}

// Round 9
// 573.730 us; speedup vs baseline: 1.6074x; 1.0507x over previous
//
#include <hip/hip_runtime.h>
#include <hip/hip_fp16.h>
#include <math.h>

#define NN   20000
#define EE   320000
#define RR   4

typedef unsigned short u16;
typedef unsigned int   u32;
typedef _Float16 half8v __attribute__((ext_vector_type(8)));
typedef _Float16 v2h    __attribute__((ext_vector_type(2)));
typedef __attribute__((ext_vector_type(4))) float f32x4;

static __device__ __forceinline__ u16 f2h(float f){ return __half_as_ushort(__float2half_rn(f)); }
static __device__ __forceinline__ v2h u2v(u32 u){ union{u32 u; v2h v;} c; c.u=u; return c.v; }
static __device__ __forceinline__ u32 v2u(v2h v){ union{u32 u; v2h v;} c; c.v=v; return c.u; }
static __device__ __forceinline__ v2h splat2(float f){ v2h r; r[0]=(_Float16)f; r[1]=(_Float16)f; return r; }
static __device__ __forceinline__ float fdot2(v2h a, v2h b, float c){
  return __builtin_amdgcn_fdot2(a, b, c, false);
}
static __device__ __forceinline__ void gload_lds16(const void* g, void* l){
  __builtin_amdgcn_global_load_lds((const __attribute__((address_space(1))) void*)g,
                                   (__attribute__((address_space(3))) void*)l, 16, 0, 0);
}

// ---------------- CSR build ----------------
__global__ void k_zero_int(int* __restrict__ p, int n){
  int i = blockIdx.x*blockDim.x + threadIdx.x;
  if (i < n) p[i] = 0;
}
__global__ void k_countA(const int* __restrict__ ei, int* __restrict__ deg4){
  int i = blockIdx.x*blockDim.x + threadIdx.x;
  if (i < RR*EE) {
    int r = i / EE, e = i % EE;
    int d = ei[(size_t)r*2*EE + EE + e];
    atomicAdd(&deg4[r*NN + d], 1);
  }
}
__global__ __launch_bounds__(1024) void k_scan(const int* __restrict__ cnt_all, int* __restrict__ off_all,
                                               int* __restrict__ cur_all, int n){
  const int* cnt = cnt_all + (size_t)blockIdx.x*n;
  int* off = off_all + (size_t)blockIdx.x*(n+1);
  int* cur = cur_all + (size_t)blockIdx.x*n;
  __shared__ int part[1024];
  int t = threadIdx.x;
  int chunk = (n + 1023) >> 10;
  int lo = t*chunk; if (lo > n) lo = n;
  int hi = lo + chunk; if (hi > n) hi = n;
  int s = 0;
  for (int i = lo; i < hi; ++i) s += cnt[i];
  part[t] = s;
  __syncthreads();
  for (int d = 1; d < 1024; d <<= 1) {
    int u = (t >= d) ? part[t-d] : 0;
    __syncthreads();
    part[t] += u;
    __syncthreads();
  }
  int run = (t == 0) ? 0 : part[t-1];
  for (int i = lo; i < hi; ++i) { off[i] = run; cur[i] = run; run += cnt[i]; }
  if (t == 1023) off[n] = part[1023];
}
// scatter: 4 dst-range passes keep the random 4B writes L2-local
__global__ void k_scatter4(const int* __restrict__ ei, int* __restrict__ cur4, int* __restrict__ csr4,
                           int dlo, int dhi){
  int i = blockIdx.x*blockDim.x + threadIdx.x;
  if (i < RR*EE) {
    int r = i / EE, e = i % EE;
    int d = ei[(size_t)r*2*EE + EE + e];
    if (d >= dlo && d < dhi) {
      int s = ei[(size_t)r*2*EE + e];
      int p = atomicAdd(&cur4[r*NN + d], 1);
      csr4[(size_t)r*EE + p] = s;
    }
  }
}

// ---------------- prep: f32 -> f16 cast / transposed-packed weights ----------------
__global__ void k_cast(const float* __restrict__ x, u16* __restrict__ o, int n4){
  int i = blockIdx.x*blockDim.x + threadIdx.x;
  if (i < n4) {
    float4 v = reinterpret_cast<const float4*>(x)[i];
    ushort4 b;
    b.x = f2h(v.x); b.y = f2h(v.y); b.z = f2h(v.z); b.w = f2h(v.w);
    reinterpret_cast<ushort4*>(o)[i] = b;
  }
}
// dst[r][n][k] f16 with n in [0,2N): n<N from A (=A^T), else from B. src f32 [r][K][N].
__global__ void k_prep(const float* __restrict__ A, const float* __restrict__ B,
                       u16* __restrict__ dst, int K, int N, int total){
  int i = blockIdx.x*blockDim.x + threadIdx.x;
  if (i >= total) return;
  int k = i % K;
  int n = (i / K) % (2*N);
  int r = i / (K*2*N);
  const float* S = (n < N) ? A : B;
  int nn = (n < N) ? n : n - N;
  dst[i] = f2h(S[((size_t)r*K + k)*N + nn]);
}

// ---------------- MFMA GEMM (f16): Cb = A@BT^T; z-batched ----------------
__global__ __launch_bounds__(256) void k_mfma(
    const u16* __restrict__ A, const u16* __restrict__ BT,
    int M, int K, u16* __restrict__ Cb, int ldc,
    long aZ, long btZ, long cZ)
{
  constexpr int BM = 128, BN = 128;
  constexpr int FI = 4, FJ = 4;
  const int zz = blockIdx.z;
  A  += (size_t)zz*aZ;
  BT += (size_t)zz*btZ;
  Cb += (size_t)zz*cZ;

  __shared__ u16 As[BM*32];
  __shared__ u16 Bs[BN*32];
  const int t = threadIdx.x;
  const int lane = t & 63, wid = t >> 6;
  const int wr = wid >> 1, wc = wid & 1;
  const int bm = blockIdx.x * BM, bn = blockIdx.y * BN;
  const int lr = lane & 15, lk = lane >> 4;

  f32x4 acc[FI][FJ];
  #pragma unroll
  for (int i = 0; i < FI; ++i)
    #pragma unroll
    for (int j = 0; j < FJ; ++j) acc[i][j] = (f32x4)(0.f);

  const int nk = K >> 5;
  char* AsB = (char*)As;
  char* BsB = (char*)Bs;

  for (int s = 0; s < nk; ++s) {
    const int kk = s << 5;
    #pragma unroll
    for (int i = 0; i < 2; ++i) {
      int c = t + 256*i;
      int row = c >> 2, sub = c & 3;
      int lsub = sub ^ (row & 3);
      int grow = bm + row; if (grow >= M) grow = M - 1;
      gload_lds16(A + (size_t)grow*K + kk + lsub*8, AsB + c*16);
    }
    #pragma unroll
    for (int i = 0; i < 2; ++i) {
      int c = t + 256*i;
      int row = c >> 2, sub = c & 3;
      int lsub = sub ^ (row & 3);
      gload_lds16(BT + (size_t)(bn + row)*K + kk + lsub*8, BsB + c*16);
    }
    __syncthreads();
    half8v a[FI], b[FJ];
    #pragma unroll
    for (int i = 0; i < FI; ++i) {
      int row = wr*64 + i*16 + lr;
      int sub = lk ^ (row & 3);
      a[i] = *reinterpret_cast<half8v*>(AsB + row*64 + sub*16);
    }
    #pragma unroll
    for (int j = 0; j < FJ; ++j) {
      int col = wc*64 + j*16 + lr;
      int sub = lk ^ (col & 3);
      b[j] = *reinterpret_cast<half8v*>(BsB + col*64 + sub*16);
    }
    #pragma unroll
    for (int i = 0; i < FI; ++i)
      #pragma unroll
      for (int j = 0; j < FJ; ++j)
        acc[i][j] = __builtin_amdgcn_mfma_f32_16x16x32_f16(a[i], b[j], acc[i][j], 0, 0, 0);
    __syncthreads();
  }

  #pragma unroll
  for (int i = 0; i < FI; ++i) {
    #pragma unroll
    for (int j = 0; j < FJ; ++j) {
      int col = bn + wc*64 + j*16 + lr;
      #pragma unroll
      for (int q = 0; q < 4; ++q) {
        int row = bm + wr*64 + i*16 + lk*4 + q;
        if (row < M) Cb[(size_t)row*ldc + col] = f2h(acc[i][j][q]);
      }
    }
  }
}

// ---------------- GATv2 attention: f16 packed, 8 ch/lane, 8 edges/iter (4 per sub-half) ----------------
// xlr [NN][2048]: relation z occupies cols z*512..z*512+511 (0-255 xl, 256-511 xr).
// Weight scaling: w = exp2(p - 6) (power-of-2 scale cancels in a/s; keeps w in f16 range, cap 2^12).
__global__ __launch_bounds__(256) void k_gat(
    const u16* __restrict__ xlr,
    const float* __restrict__ att, const float* __restrict__ bias,
    const int* __restrict__ off4, const int* __restrict__ csr4,
    u16* __restrict__ out)
{
  const int z = blockIdx.z;
  int node = blockIdx.x*4 + (threadIdx.x >> 6);
  if (node >= NN) return;
  const int lane = threadIdx.x & 63;
  const int sl = lane & 31, sub = lane >> 5;
  const u16* xbase = xlr + (size_t)z*512;
  const int* off = off4 + (size_t)z*(NN+1);
  const int* csr = csr4 + (size_t)z*EE;
  u16* outp = out + (size_t)z*(size_t)NN*256;

  const int co = sl*8;
  const u16* selfrow = xbase + (size_t)node*2048;
  const v2h c02 = splat2(0.2f);
  const float L2E = 1.4426950408889634f;

  uint4 rx = *reinterpret_cast<const uint4*>(selfrow + 256 + co);
  v2h xr2[4] = {u2v(rx.x), u2v(rx.y), u2v(rx.z), u2v(rx.w)};
  v2h av2[4];
  {
    float4 q0 = *reinterpret_cast<const float4*>(att + z*256 + co);
    float4 q1 = *reinterpret_cast<const float4*>(att + z*256 + co + 4);
    av2[0][0]=(_Float16)(q0.x*L2E); av2[0][1]=(_Float16)(q0.y*L2E);
    av2[1][0]=(_Float16)(q0.z*L2E); av2[1][1]=(_Float16)(q0.w*L2E);
    av2[2][0]=(_Float16)(q1.x*L2E); av2[2][1]=(_Float16)(q1.y*L2E);
    av2[3][0]=(_Float16)(q1.z*L2E); av2[3][1]=(_Float16)(q1.w*L2E);
  }
  // self loop (sub 0 only)
  uint4 sx = *reinterpret_cast<const uint4*>(selfrow + co);
  v2h xs2[4] = {u2v(sx.x), u2v(sx.y), u2v(sx.z), u2v(sx.w)};
  float ps = 0.f;
  #pragma unroll
  for (int i = 0; i < 4; ++i) {
    v2h zz = xs2[i] + xr2[i];
    v2h lr = __builtin_elementwise_max(zz, zz*c02);
    ps = fdot2(av2[i], lr, ps);
  }
  ps += __shfl_xor(ps,1); ps += __shfl_xor(ps,2); ps += __shfl_xor(ps,4);
  float wsf = (sub == 0) ? exp2f(fminf(ps - 6.f, 12.f)) : 0.f;
  float s = wsf;
  v2h a2[4];
  {
    v2h w2 = splat2(wsf);
    #pragma unroll
    for (int i = 0; i < 4; ++i) a2[i] = w2*xs2[i];
  }

  const int e0 = off[node], e1 = off[node+1];
  const int e1m1 = e1 - 1;
  for (int k = e0; k < e1; k += 8) {             // 8 edges/iter: 4 per sub-half
    v2h xv[4][4];
    float p[4];
    int kks[4];
    #pragma unroll
    for (int j = 0; j < 4; ++j) {
      int kk = k + 2*j + sub;
      kks[j] = kk;
      int idx = csr[kk <= e1m1 ? kk : e1m1];
      uint4 v = *reinterpret_cast<const uint4*>(xbase + (size_t)idx*2048 + co);
      xv[j][0]=u2v(v.x); xv[j][1]=u2v(v.y); xv[j][2]=u2v(v.z); xv[j][3]=u2v(v.w);
      float pp = 0.f;
      #pragma unroll
      for (int i = 0; i < 4; ++i) {
        v2h zz = xv[j][i] + xr2[i];
        v2h lr = __builtin_elementwise_max(zz, zz*c02);
        pp = fdot2(av2[i], lr, pp);
      }
      p[j] = pp;
    }
    #pragma unroll
    for (int j = 0; j < 4; ++j) {
      p[j] += __shfl_xor(p[j],1);
      p[j] += __shfl_xor(p[j],2);
      p[j] += __shfl_xor(p[j],4);
    }
    float w[4];
    #pragma unroll
    for (int j = 0; j < 4; ++j)
      w[j] = (kks[j] < e1) ? exp2f(fminf(p[j] - 6.f, 12.f)) : 0.f;
    s += (w[0] + w[1]) + (w[2] + w[3]);
    #pragma unroll
    for (int j = 0; j < 4; ++j) {
      v2h w2 = splat2(w[j]);
      #pragma unroll
      for (int i = 0; i < 4; ++i) a2[i] += w2*xv[j][i];
    }
  }
  // combine sub-halves
  s += __shfl_xor(s, 32);
  #pragma unroll
  for (int i = 0; i < 4; ++i) {
    u32 t = (u32)__shfl_xor((int)v2u(a2[i]), 32);
    a2[i] += u2v(t);
  }
  float inv = 1.f / s;
  if (sub == 0) {
    float4 b0 = *reinterpret_cast<const float4*>(bias + z*256 + co);
    float4 b1 = *reinterpret_cast<const float4*>(bias + z*256 + co + 4);
    float bv[8] = {b0.x,b0.y,b0.z,b0.w,b1.x,b1.y,b1.z,b1.w};
    u32 o[4];
    #pragma unroll
    for (int i = 0; i < 4; ++i) {
      float lo = fmaxf((float)a2[i][0]*inv + bv[2*i],   0.f);
      float hi = fmaxf((float)a2[i][1]*inv + bv[2*i+1], 0.f);
      o[i] = (u32)f2h(lo) | ((u32)f2h(hi) << 16);
    }
    uint4 ov = {o[0], o[1], o[2], o[3]};
    *reinterpret_cast<uint4*>(outp + (size_t)node*256 + co) = ov;
  }
}

// ---------------- GraphConv: aggregate projected P-slice; 16-lane groups, 4 ch/lane ----------------
// C [R][NN][128] f16 = [P|Q]; result = act(sum_j P[j] + Q[i] + bias).
// Group g = lane>>4 owns edges k+2g..k+2g+1 (8 edges/iter, 4 gathers in flight).
// Packed f16 accumulation (values O(0.5), deg~16 -> |sum| < 16; f16 eps ~0.008 at that scale).
template<int RELU, int F32OUT>
__global__ __launch_bounds__(256) void k_aggp(
    const u16* __restrict__ C, const float* __restrict__ bias,
    const int* __restrict__ off4, const int* __restrict__ csr4,
    u16* __restrict__ outb, float* __restrict__ outf)
{
  const int z = blockIdx.z;
  int node = blockIdx.x*4 + (threadIdx.x >> 6);
  if (node >= NN) return;
  const int lane = threadIdx.x & 63;
  const int g = lane >> 4, sl = lane & 15;
  const u16* Cp = C + (size_t)z*(size_t)NN*128;
  const int* off = off4 + (size_t)z*(NN+1);
  const int* csr = csr4 + (size_t)z*EE;
  const int co = sl*4;                      // 4 channels per lane
  v2h acc0 = splat2(0.f), acc1 = splat2(0.f);
  const int e0 = off[node], e1 = off[node+1];
  const int e1m1 = e1 - 1;
  for (int k = e0; k < e1; k += 8) {        // 8 edges/iter: 2 per 16-lane group
    #pragma unroll
    for (int j = 0; j < 2; ++j) {
      int kk = k + 2*g + j;
      int idx = csr[kk <= e1m1 ? kk : e1m1];
      uint2 v = *reinterpret_cast<const uint2*>(Cp + (size_t)idx*128 + co);
      bool val = kk < e1;
      u32 vx = val ? v.x : 0u;
      u32 vy = val ? v.y : 0u;
      acc0 += u2v(vx);
      acc1 += u2v(vy);
    }
  }
  // cross-group reduce in f32
  float a0 = (float)acc0[0], a1 = (float)acc0[1];
  float a2 = (float)acc1[0], a3 = (float)acc1[1];
  a0 += __shfl_xor(a0,16); a1 += __shfl_xor(a1,16);
  a2 += __shfl_xor(a2,16); a3 += __shfl_xor(a3,16);
  a0 += __shfl_xor(a0,32); a1 += __shfl_xor(a1,32);
  a2 += __shfl_xor(a2,32); a3 += __shfl_xor(a3,32);
  if (g == 0) {
    uint2 q = *reinterpret_cast<const uint2*>(Cp + (size_t)node*128 + 64 + co);
    v2h q0 = u2v(q.x), q1 = u2v(q.y);
    float4 bv = *reinterpret_cast<const float4*>(bias + z*64 + co);
    float v0 = a0 + (float)q0[0] + bv.x;
    float v1 = a1 + (float)q0[1] + bv.y;
    float v2 = a2 + (float)q1[0] + bv.z;
    float v3 = a3 + (float)q1[1] + bv.w;
    if (RELU) {
      v0 = fmaxf(v0, 0.f); v1 = fmaxf(v1, 0.f);
      v2 = fmaxf(v2, 0.f); v3 = fmaxf(v3, 0.f);
    }
    if (F32OUT) {
      float4 o = {v0, v1, v2, v3};
      *reinterpret_cast<float4*>(outf + (size_t)node*256 + z*64 + co) = o;
    } else {
      uint2 o;
      o.x = (u32)f2h(v0) | ((u32)f2h(v1) << 16);
      o.y = (u32)f2h(v2) | ((u32)f2h(v3) << 16);
      *reinterpret_cast<uint2*>(outb + ((size_t)z*NN + node)*64 + co) = o;
    }
  }
}

// ---------------- orchestration ----------------
extern "C" void kernel_launch(void* const* d_in, const int* in_sizes, int n_in,
                              void* d_out, int out_size, void* d_ws, size_t ws_size,
                              hipStream_t stream)
{
  const float* x      = (const float*)d_in[0];
  const int*   ei     = (const int*)  d_in[1];
  const float* Wl1    = (const float*)d_in[2];
  const float* Wr1    = (const float*)d_in[3];
  const float* att1   = (const float*)d_in[4];
  const float* b1     = (const float*)d_in[5];
  const float* Wl2    = (const float*)d_in[6];
  const float* Wr2    = (const float*)d_in[7];
  const float* att2   = (const float*)d_in[8];
  const float* b2     = (const float*)d_in[9];
  const float* Wrel3  = (const float*)d_in[10];
  const float* Wroot3 = (const float*)d_in[11];
  const float* b3     = (const float*)d_in[12];
  const float* Wrel4  = (const float*)d_in[13];
  const float* Wroot4 = (const float*)d_in[14];
  const float* b4     = (const float*)d_in[15];
  float* out = (float*)d_out;

  const dim3 thr(256);
  const size_t NB2048 = (size_t)NN*2048;
  const size_t NB256  = (size_t)NN*256;
  const size_t NB128  = (size_t)NN*128;
  const size_t NB64   = (size_t)NN*64;

  u16* XLR = (u16*)d_ws;                          // [NN][2048] (all relations side by side)
  u16* h   = XLR + NB2048;                        // [R][NN][256]
  u16* xbf = h   + NB256*RR;                      // [NN][256]
  u16* W1T = xbf + NB256;                         // [2048][256] (= [R][512][256])
  u16* W2T = W1T + (size_t)RR*512*256;
  u16* W3T = W2T + (size_t)RR*512*256;            // [R][128][256]
  u16* W4T = W3T + (size_t)RR*128*256;            // [R][128][64]
  int* deg4 = (int*)(W4T + (size_t)RR*128*64);
  int* off4 = deg4 + RR*NN;
  int* cur4 = off4 + RR*(NN+1);
  int* csr4 = cur4 + RR*NN;                       // R*EE
  u16* C34 = XLR;                                 // [R][NN][128] aliases XLR
  u16* h3b = XLR + NB128*RR;                      // [R][NN][64]  aliases XLR (disjoint)

  // prep
  k_cast<<<dim3((NN*256/4+255)/256), thr, 0, stream>>>(x, xbf, NN*256/4);
  k_prep<<<dim3((RR*512*256+255)/256), thr, 0, stream>>>(Wl1, Wr1, W1T, 256, 256, RR*512*256);
  k_prep<<<dim3((RR*512*256+255)/256), thr, 0, stream>>>(Wl2, Wr2, W2T, 256, 256, RR*512*256);
  k_prep<<<dim3((RR*128*256+255)/256), thr, 0, stream>>>(Wrel3, Wroot3, W3T, 256, 64, RR*128*256);
  k_prep<<<dim3((RR*128*64+255)/256),  thr, 0, stream>>>(Wrel4, Wroot4, W4T, 64, 64, RR*128*64);

  // CSR
  k_zero_int<<<dim3((RR*NN+255)/256), thr, 0, stream>>>(deg4, RR*NN);
  k_countA  <<<dim3((RR*EE+255)/256), thr, 0, stream>>>(ei, deg4);
  k_scan    <<<dim3(RR), dim3(1024), 0, stream>>>(deg4, off4, cur4, NN);
  for (int p = 0; p < 4; ++p)
    k_scatter4<<<dim3((RR*EE+255)/256), thr, 0, stream>>>(ei, cur4, csr4, p*5000, (p+1)*5000);

  const dim3 gNode(5000, 1, RR);
  // L1: XLR = xbf @ W1T^T  (single fused GEMM, N=2048)
  k_mfma<<<dim3(157,16,1), thr, 0, stream>>>(xbf, W1T, NN, 256, XLR, 2048, 0, 0, 0);
  k_gat<<<gNode, thr, 0, stream>>>(XLR, att1, b1, off4, csr4, h);
  // L2: per-z GEMM back into XLR column slices
  k_mfma<<<dim3(157,4,RR), thr, 0, stream>>>(h, W2T, NN, 256, XLR, 2048,
                                             (long)NB256, 512*256, 512);
  k_gat<<<gNode, thr, 0, stream>>>(XLR, att2, b2, off4, csr4, h);
  // L3: C34[z] = h[z] @ [Wrel3|Wroot3][z] ; h3 = relu(aggP + Q + b3)
  k_mfma<<<dim3(157,1,RR), thr, 0, stream>>>(h, W3T, NN, 256, C34, 128,
                                             (long)NB256, 128*256, (long)NB128);
  k_aggp<1,0><<<gNode, thr, 0, stream>>>(C34, b3, off4, csr4, h3b, nullptr);
  // L4: C34[z] = h3[z] @ [Wrel4|Wroot4][z] ; out[:,z,:] = aggP + Q + b4
  k_mfma<<<dim3(157,1,RR), thr, 0, stream>>>(h3b, W4T, NN, 64, C34, 128,
                                             (long)NB64, 128*64, (long)NB128);
  k_aggp<0,1><<<gNode, thr, 0, stream>>>(C34, b4, off4, csr4, nullptr, out);
}

// Round 10
// 562.931 us; speedup vs baseline: 1.6382x; 1.0192x over previous
//
#include <hip/hip_runtime.h>
#include <hip/hip_fp16.h>
#include <math.h>

#define NN   20000
#define EE   320000
#define RR   4

typedef unsigned short u16;
typedef unsigned int   u32;
typedef _Float16 half8v __attribute__((ext_vector_type(8)));
typedef _Float16 v2h    __attribute__((ext_vector_type(2)));
typedef __attribute__((ext_vector_type(4))) float f32x4;

static __device__ __forceinline__ u16 f2h(float f){ return __half_as_ushort(__float2half_rn(f)); }
static __device__ __forceinline__ v2h u2v(u32 u){ union{u32 u; v2h v;} c; c.u=u; return c.v; }
static __device__ __forceinline__ u32 v2u(v2h v){ union{u32 u; v2h v;} c; c.v=v; return c.u; }
static __device__ __forceinline__ v2h splat2(float f){ v2h r; r[0]=(_Float16)f; r[1]=(_Float16)f; return r; }
static __device__ __forceinline__ float fdot2(v2h a, v2h b, float c){
  return __builtin_amdgcn_fdot2(a, b, c, false);
}
static __device__ __forceinline__ void gload_lds16(const void* g, void* l){
  __builtin_amdgcn_global_load_lds((const __attribute__((address_space(1))) void*)g,
                                   (__attribute__((address_space(3))) void*)l, 16, 0, 0);
}

// ---------------- CSR build ----------------
__global__ void k_zero_int(int* __restrict__ p, int n){
  int i = blockIdx.x*blockDim.x + threadIdx.x;
  if (i < n) p[i] = 0;
}
__global__ void k_countA(const int* __restrict__ ei, int* __restrict__ deg4){
  int i = blockIdx.x*blockDim.x + threadIdx.x;
  if (i < RR*EE) {
    int r = i / EE, e = i % EE;
    int d = ei[(size_t)r*2*EE + EE + e];
    atomicAdd(&deg4[r*NN + d], 1);
  }
}
__global__ __launch_bounds__(1024) void k_scan(const int* __restrict__ cnt_all, int* __restrict__ off_all,
                                               int* __restrict__ cur_all, int n){
  const int* cnt = cnt_all + (size_t)blockIdx.x*n;
  int* off = off_all + (size_t)blockIdx.x*(n+1);
  int* cur = cur_all + (size_t)blockIdx.x*n;
  __shared__ int part[1024];
  int t = threadIdx.x;
  int chunk = (n + 1023) >> 10;
  int lo = t*chunk; if (lo > n) lo = n;
  int hi = lo + chunk; if (hi > n) hi = n;
  int s = 0;
  for (int i = lo; i < hi; ++i) s += cnt[i];
  part[t] = s;
  __syncthreads();
  for (int d = 1; d < 1024; d <<= 1) {
    int u = (t >= d) ? part[t-d] : 0;
    __syncthreads();
    part[t] += u;
    __syncthreads();
  }
  int run = (t == 0) ? 0 : part[t-1];
  for (int i = lo; i < hi; ++i) { off[i] = run; cur[i] = run; run += cnt[i]; }
  if (t == 1023) off[n] = part[1023];
}
// merged scatter: pass = blockIdx.x/5000 (dispatch order preserves dst-range L2 locality).
// csr stores BYTE offset of the source row in XLR: src*4096 (2048 f16 elems * 2B).
__global__ void k_scatterM(const int* __restrict__ ei, int* __restrict__ cur4, u32* __restrict__ csr4){
  int bid = blockIdx.x;
  int pass = bid / 5000;
  int i = (bid - pass*5000)*256 + threadIdx.x;
  int dlo = pass*5000, dhi = dlo + 5000;
  if (i < RR*EE) {
    int r = i / EE, e = i - r*EE;
    int d = ei[(size_t)r*2*EE + EE + e];
    if (d >= dlo && d < dhi) {
      int s = ei[(size_t)r*2*EE + e];
      int p = atomicAdd(&cur4[r*NN + d], 1);
      csr4[(size_t)r*EE + p] = (u32)s * 4096u;
    }
  }
}

// ---------------- fused prep: cast + 4 weight transposes in one dispatch ----------------
static __device__ __forceinline__ void prep_body(const float* A, const float* B, u16* dst,
                                                 int K, int N, int total, int i){
  if (i >= total) return;
  int k = i % K;
  int n = (i / K) % (2*N);
  int r = i / (K*2*N);
  const float* S = (n < N) ? A : B;
  int nn = (n < N) ? n : n - N;
  dst[i] = f2h(S[((size_t)r*K + k)*N + nn]);
}
__global__ void k_prepall(const float* __restrict__ x, u16* __restrict__ xbf,
                          const float* __restrict__ Wl1, const float* __restrict__ Wr1, u16* __restrict__ W1T,
                          const float* __restrict__ Wl2, const float* __restrict__ Wr2, u16* __restrict__ W2T,
                          const float* __restrict__ W3a, const float* __restrict__ W3b, u16* __restrict__ W3T,
                          const float* __restrict__ W4a, const float* __restrict__ W4b, u16* __restrict__ W4T){
  int kind = blockIdx.y;
  int i = blockIdx.x*256 + threadIdx.x;
  if (kind == 0) {                                  // x f32 -> f16, float4-wide
    if (i < NN*256/4) {
      float4 v = reinterpret_cast<const float4*>(x)[i];
      ushort4 b;
      b.x = f2h(v.x); b.y = f2h(v.y); b.z = f2h(v.z); b.w = f2h(v.w);
      reinterpret_cast<ushort4*>(xbf)[i] = b;
    }
  } else if (kind == 1) prep_body(Wl1, Wr1, W1T, 256, 256, RR*512*256, i);
  else if (kind == 2)   prep_body(Wl2, Wr2, W2T, 256, 256, RR*512*256, i);
  else if (kind == 3)   prep_body(W3a, W3b, W3T, 256, 64,  RR*128*256, i);
  else                  prep_body(W4a, W4b, W4T, 64,  64,  RR*128*64,  i);
}

// ---------------- MFMA GEMM (f16): Cb = A@BT^T; z-batched ----------------
__global__ __launch_bounds__(256) void k_mfma(
    const u16* __restrict__ A, const u16* __restrict__ BT,
    int M, int K, u16* __restrict__ Cb, int ldc,
    long aZ, long btZ, long cZ)
{
  constexpr int BM = 128, BN = 128;
  constexpr int FI = 4, FJ = 4;
  const int zz = blockIdx.z;
  A  += (size_t)zz*aZ;
  BT += (size_t)zz*btZ;
  Cb += (size_t)zz*cZ;

  __shared__ u16 As[BM*32];
  __shared__ u16 Bs[BN*32];
  const int t = threadIdx.x;
  const int lane = t & 63, wid = t >> 6;
  const int wr = wid >> 1, wc = wid & 1;
  const int bm = blockIdx.x * BM, bn = blockIdx.y * BN;
  const int lr = lane & 15, lk = lane >> 4;

  f32x4 acc[FI][FJ];
  #pragma unroll
  for (int i = 0; i < FI; ++i)
    #pragma unroll
    for (int j = 0; j < FJ; ++j) acc[i][j] = (f32x4)(0.f);

  const int nk = K >> 5;
  char* AsB = (char*)As;
  char* BsB = (char*)Bs;

  for (int s = 0; s < nk; ++s) {
    const int kk = s << 5;
    #pragma unroll
    for (int i = 0; i < 2; ++i) {
      int c = t + 256*i;
      int row = c >> 2, sub = c & 3;
      int lsub = sub ^ (row & 3);
      int grow = bm + row; if (grow >= M) grow = M - 1;
      gload_lds16(A + (size_t)grow*K + kk + lsub*8, AsB + c*16);
    }
    #pragma unroll
    for (int i = 0; i < 2; ++i) {
      int c = t + 256*i;
      int row = c >> 2, sub = c & 3;
      int lsub = sub ^ (row & 3);
      gload_lds16(BT + (size_t)(bn + row)*K + kk + lsub*8, BsB + c*16);
    }
    __syncthreads();
    half8v a[FI], b[FJ];
    #pragma unroll
    for (int i = 0; i < FI; ++i) {
      int row = wr*64 + i*16 + lr;
      int sub = lk ^ (row & 3);
      a[i] = *reinterpret_cast<half8v*>(AsB + row*64 + sub*16);
    }
    #pragma unroll
    for (int j = 0; j < FJ; ++j) {
      int col = wc*64 + j*16 + lr;
      int sub = lk ^ (col & 3);
      b[j] = *reinterpret_cast<half8v*>(BsB + col*64 + sub*16);
    }
    #pragma unroll
    for (int i = 0; i < FI; ++i)
      #pragma unroll
      for (int j = 0; j < FJ; ++j)
        acc[i][j] = __builtin_amdgcn_mfma_f32_16x16x32_f16(a[i], b[j], acc[i][j], 0, 0, 0);
    __syncthreads();
  }

  #pragma unroll
  for (int i = 0; i < FI; ++i) {
    #pragma unroll
    for (int j = 0; j < FJ; ++j) {
      int col = bn + wc*64 + j*16 + lr;
      #pragma unroll
      for (int q = 0; q < 4; ++q) {
        int row = bm + wr*64 + i*16 + lk*4 + q;
        if (row < M) Cb[(size_t)row*ldc + col] = f2h(acc[i][j][q]);
      }
    }
  }
}

// ---------------- GATv2 attention: f16 packed, unpredicated main loop + tail ----------------
// xlr [NN][2048]: relation z at cols z*512.. (0-255 xl, 256-511 xr). csr holds src*4096 byte offsets.
// Weight scaling: w = exp2(p - 6) (power-of-2 scale cancels in a/s; cap 2^12 guards overflow).
__global__ __launch_bounds__(256) void k_gat(
    const u16* __restrict__ xlr,
    const float* __restrict__ att, const float* __restrict__ bias,
    const int* __restrict__ off4, const u32* __restrict__ csr4,
    u16* __restrict__ out)
{
  const int z = blockIdx.z;
  int node = blockIdx.x*4 + (threadIdx.x >> 6);
  if (node >= NN) return;
  const int lane = threadIdx.x & 63;
  const int sl = lane & 31, sub = lane >> 5;
  const int* off = off4 + (size_t)z*(NN+1);
  const u32* csr = csr4 + (size_t)z*EE;
  u16* outp = out + (size_t)z*(size_t)NN*256;

  const int co = sl*8;
  // per-lane byte base into the z-slice, at this lane's channel offset
  const char* xc = (const char*)xlr + (size_t)z*1024 + co*2;
  const u16* selfrow = xlr + (size_t)z*512 + (size_t)node*2048;
  const v2h c02 = splat2(0.2f);
  const float L2E = 1.4426950408889634f;

  uint4 rx = *reinterpret_cast<const uint4*>(selfrow + 256 + co);
  v2h xr2[4] = {u2v(rx.x), u2v(rx.y), u2v(rx.z), u2v(rx.w)};
  v2h av2[4];
  {
    float4 q0 = *reinterpret_cast<const float4*>(att + z*256 + co);
    float4 q1 = *reinterpret_cast<const float4*>(att + z*256 + co + 4);
    av2[0][0]=(_Float16)(q0.x*L2E); av2[0][1]=(_Float16)(q0.y*L2E);
    av2[1][0]=(_Float16)(q0.z*L2E); av2[1][1]=(_Float16)(q0.w*L2E);
    av2[2][0]=(_Float16)(q1.x*L2E); av2[2][1]=(_Float16)(q1.y*L2E);
    av2[3][0]=(_Float16)(q1.z*L2E); av2[3][1]=(_Float16)(q1.w*L2E);
  }
  // self loop (sub 0 only)
  uint4 sx = *reinterpret_cast<const uint4*>(selfrow + co);
  v2h xs2[4] = {u2v(sx.x), u2v(sx.y), u2v(sx.z), u2v(sx.w)};
  float ps = 0.f;
  #pragma unroll
  for (int i = 0; i < 4; ++i) {
    v2h zz = xs2[i] + xr2[i];
    v2h lr = __builtin_elementwise_max(zz, zz*c02);
    ps = fdot2(av2[i], lr, ps);
  }
  ps += __shfl_xor(ps,1); ps += __shfl_xor(ps,2); ps += __shfl_xor(ps,4);
  float wsf = (sub == 0) ? exp2f(fminf(ps - 6.f, 12.f)) : 0.f;
  float s = wsf;
  v2h a2[4];
  {
    v2h w2 = splat2(wsf);
    #pragma unroll
    for (int i = 0; i < 4; ++i) a2[i] = w2*xs2[i];
  }

  const int e0 = off[node], e1 = off[node+1];
  const int kfull = e0 + ((e1 - e0) & ~7);
  // main loop: full 8-edge chunks, NO predication (all indices valid)
  for (int k = e0; k < kfull; k += 8) {
    v2h xv[4][4];
    float p[4];
    #pragma unroll
    for (int j = 0; j < 4; ++j) {
      u32 boff = csr[k + 2*j + sub];
      uint4 v = *reinterpret_cast<const uint4*>(xc + boff);
      xv[j][0]=u2v(v.x); xv[j][1]=u2v(v.y); xv[j][2]=u2v(v.z); xv[j][3]=u2v(v.w);
      float pp = 0.f;
      #pragma unroll
      for (int i = 0; i < 4; ++i) {
        v2h zz = xv[j][i] + xr2[i];
        v2h lr = __builtin_elementwise_max(zz, zz*c02);
        pp = fdot2(av2[i], lr, pp);
      }
      p[j] = pp;
    }
    #pragma unroll
    for (int j = 0; j < 4; ++j) {
      p[j] += __shfl_xor(p[j],1);
      p[j] += __shfl_xor(p[j],2);
      p[j] += __shfl_xor(p[j],4);
    }
    float w[4];
    #pragma unroll
    for (int j = 0; j < 4; ++j) w[j] = exp2f(fminf(p[j] - 6.f, 12.f));
    s += (w[0] + w[1]) + (w[2] + w[3]);
    #pragma unroll
    for (int j = 0; j < 4; ++j) {
      v2h w2 = splat2(w[j]);
      #pragma unroll
      for (int i = 0; i < 4; ++i) a2[i] += w2*xv[j][i];
    }
  }
  // tail: up to 7 edges, 2 per iter (1 per sub-half), predicated
  for (int k = kfull; k < e1; k += 2) {
    int kk = k + sub;
    bool val = kk < e1;
    u32 boff = csr[val ? kk : e1-1];
    uint4 v = *reinterpret_cast<const uint4*>(xc + boff);
    v2h xv[4] = {u2v(v.x), u2v(v.y), u2v(v.z), u2v(v.w)};
    float pp = 0.f;
    #pragma unroll
    for (int i = 0; i < 4; ++i) {
      v2h zz = xv[i] + xr2[i];
      v2h lr = __builtin_elementwise_max(zz, zz*c02);
      pp = fdot2(av2[i], lr, pp);
    }
    pp += __shfl_xor(pp,1); pp += __shfl_xor(pp,2); pp += __shfl_xor(pp,4);
    float w = val ? exp2f(fminf(pp - 6.f, 12.f)) : 0.f;
    s += w;
    v2h w2 = splat2(w);
    #pragma unroll
    for (int i = 0; i < 4; ++i) a2[i] += w2*xv[i];
  }
  // combine sub-halves
  s += __shfl_xor(s, 32);
  #pragma unroll
  for (int i = 0; i < 4; ++i) {
    u32 t = (u32)__shfl_xor((int)v2u(a2[i]), 32);
    a2[i] += u2v(t);
  }
  float inv = 1.f / s;
  if (sub == 0) {
    float4 b0 = *reinterpret_cast<const float4*>(bias + z*256 + co);
    float4 b1 = *reinterpret_cast<const float4*>(bias + z*256 + co + 4);
    float bv[8] = {b0.x,b0.y,b0.z,b0.w,b1.x,b1.y,b1.z,b1.w};
    u32 o[4];
    #pragma unroll
    for (int i = 0; i < 4; ++i) {
      float lo = fmaxf((float)a2[i][0]*inv + bv[2*i],   0.f);
      float hi = fmaxf((float)a2[i][1]*inv + bv[2*i+1], 0.f);
      o[i] = (u32)f2h(lo) | ((u32)f2h(hi) << 16);
    }
    uint4 ov = {o[0], o[1], o[2], o[3]};
    *reinterpret_cast<uint4*>(outp + (size_t)node*256 + co) = ov;
  }
}

// ---------------- GraphConv: aggregate projected P-slice; 16-lane groups, main+tail ----------------
// C [R][NN][128] f16 = [P|Q]; result = act(sum_j P[j] + Q[i] + bias).
// csr byte offsets are src*4096; C-row byte offset = src*256 = boff>>4.
template<int RELU, int F32OUT>
__global__ __launch_bounds__(256) void k_aggp(
    const u16* __restrict__ C, const float* __restrict__ bias,
    const int* __restrict__ off4, const u32* __restrict__ csr4,
    u16* __restrict__ outb, float* __restrict__ outf)
{
  const int z = blockIdx.z;
  int node = blockIdx.x*4 + (threadIdx.x >> 6);
  if (node >= NN) return;
  const int lane = threadIdx.x & 63;
  const int g = lane >> 4, sl = lane & 15;
  const u16* Cp = C + (size_t)z*(size_t)NN*128;
  const char* Cc = (const char*)Cp + sl*8;   // 4 channels (8B) per lane
  const int* off = off4 + (size_t)z*(NN+1);
  const u32* csr = csr4 + (size_t)z*EE;
  const int co = sl*4;
  v2h acc0 = splat2(0.f), acc1 = splat2(0.f);
  const int e0 = off[node], e1 = off[node+1];
  const int kfull = e0 + ((e1 - e0) & ~7);
  for (int k = e0; k < kfull; k += 8) {      // 2 edges per 16-lane group, unpredicated
    #pragma unroll
    for (int j = 0; j < 2; ++j) {
      u32 boff = csr[k + 2*g + j] >> 4;
      uint2 v = *reinterpret_cast<const uint2*>(Cc + boff);
      acc0 += u2v(v.x);
      acc1 += u2v(v.y);
    }
  }
  for (int k = kfull; k < e1; k += 4) {      // tail: 1 edge per group, predicated
    int kk = k + g;
    bool val = kk < e1;
    u32 boff = csr[val ? kk : e1-1] >> 4;
    uint2 v = *reinterpret_cast<const uint2*>(Cc + boff);
    acc0 += u2v(val ? v.x : 0u);
    acc1 += u2v(val ? v.y : 0u);
  }
  // cross-group reduce in f32
  float a0 = (float)acc0[0], a1 = (float)acc0[1];
  float a2 = (float)acc1[0], a3 = (float)acc1[1];
  a0 += __shfl_xor(a0,16); a1 += __shfl_xor(a1,16);
  a2 += __shfl_xor(a2,16); a3 += __shfl_xor(a3,16);
  a0 += __shfl_xor(a0,32); a1 += __shfl_xor(a1,32);
  a2 += __shfl_xor(a2,32); a3 += __shfl_xor(a3,32);
  if (g == 0) {
    uint2 q = *reinterpret_cast<const uint2*>(Cp + (size_t)node*128 + 64 + co);
    v2h q0 = u2v(q.x), q1 = u2v(q.y);
    float4 bv = *reinterpret_cast<const float4*>(bias + z*64 + co);
    float v0 = a0 + (float)q0[0] + bv.x;
    float v1 = a1 + (float)q0[1] + bv.y;
    float v2 = a2 + (float)q1[0] + bv.z;
    float v3 = a3 + (float)q1[1] + bv.w;
    if (RELU) {
      v0 = fmaxf(v0, 0.f); v1 = fmaxf(v1, 0.f);
      v2 = fmaxf(v2, 0.f); v3 = fmaxf(v3, 0.f);
    }
    if (F32OUT) {
      float4 o = {v0, v1, v2, v3};
      *reinterpret_cast<float4*>(outf + (size_t)node*256 + z*64 + co) = o;
    } else {
      uint2 o;
      o.x = (u32)f2h(v0) | ((u32)f2h(v1) << 16);
      o.y = (u32)f2h(v2) | ((u32)f2h(v3) << 16);
      *reinterpret_cast<uint2*>(outb + ((size_t)z*NN + node)*64 + co) = o;
    }
  }
}

// ---------------- orchestration ----------------
extern "C" void kernel_launch(void* const* d_in, const int* in_sizes, int n_in,
                              void* d_out, int out_size, void* d_ws, size_t ws_size,
                              hipStream_t stream)
{
  const float* x      = (const float*)d_in[0];
  const int*   ei     = (const int*)  d_in[1];
  const float* Wl1    = (const float*)d_in[2];
  const float* Wr1    = (const float*)d_in[3];
  const float* att1   = (const float*)d_in[4];
  const float* b1     = (const float*)d_in[5];
  const float* Wl2    = (const float*)d_in[6];
  const float* Wr2    = (const float*)d_in[7];
  const float* att2   = (const float*)d_in[8];
  const float* b2     = (const float*)d_in[9];
  const float* Wrel3  = (const float*)d_in[10];
  const float* Wroot3 = (const float*)d_in[11];
  const float* b3     = (const float*)d_in[12];
  const float* Wrel4  = (const float*)d_in[13];
  const float* Wroot4 = (const float*)d_in[14];
  const float* b4     = (const float*)d_in[15];
  float* out = (float*)d_out;

  const dim3 thr(256);
  const size_t NB2048 = (size_t)NN*2048;
  const size_t NB256  = (size_t)NN*256;
  const size_t NB128  = (size_t)NN*128;
  const size_t NB64   = (size_t)NN*64;

  u16* XLR = (u16*)d_ws;                          // [NN][2048] (all relations side by side)
  u16* h   = XLR + NB2048;                        // [R][NN][256]
  u16* xbf = h   + NB256*RR;                      // [NN][256]
  u16* W1T = xbf + NB256;                         // [2048][256] (= [R][512][256])
  u16* W2T = W1T + (size_t)RR*512*256;
  u16* W3T = W2T + (size_t)RR*512*256;            // [R][128][256]
  u16* W4T = W3T + (size_t)RR*128*256;            // [R][128][64]
  int* deg4 = (int*)(W4T + (size_t)RR*128*64);
  int* off4 = deg4 + RR*NN;
  int* cur4 = off4 + RR*(NN+1);
  u32* csr4 = (u32*)(cur4 + RR*NN);               // R*EE (byte offsets)
  u16* C34 = XLR;                                 // [R][NN][128] aliases XLR
  u16* h3b = XLR + NB128*RR;                      // [R][NN][64]  aliases XLR (disjoint)

  // fused prep: kind 0 = cast x, kinds 1-4 = weight transposes
  k_prepall<<<dim3(5000,5), thr, 0, stream>>>(x, xbf, Wl1, Wr1, W1T, Wl2, Wr2, W2T,
                                              Wrel3, Wroot3, W3T, Wrel4, Wroot4, W4T);

  // CSR
  k_zero_int<<<dim3((RR*NN+255)/256), thr, 0, stream>>>(deg4, RR*NN);
  k_countA  <<<dim3((RR*EE+255)/256), thr, 0, stream>>>(ei, deg4);
  k_scan    <<<dim3(RR), dim3(1024), 0, stream>>>(deg4, off4, cur4, NN);
  k_scatterM<<<dim3(20000), thr, 0, stream>>>(ei, cur4, csr4);

  const dim3 gNode(5000, 1, RR);
  // L1: XLR = xbf @ W1T^T  (single fused GEMM, N=2048)
  k_mfma<<<dim3(157,16,1), thr, 0, stream>>>(xbf, W1T, NN, 256, XLR, 2048, 0, 0, 0);
  k_gat<<<gNode, thr, 0, stream>>>(XLR, att1, b1, off4, csr4, h);
  // L2: per-z GEMM back into XLR column slices
  k_mfma<<<dim3(157,4,RR), thr, 0, stream>>>(h, W2T, NN, 256, XLR, 2048,
                                             (long)NB256, 512*256, 512);
  k_gat<<<gNode, thr, 0, stream>>>(XLR, att2, b2, off4, csr4, h);
  // L3: C34[z] = h[z] @ [Wrel3|Wroot3][z] ; h3 = relu(aggP + Q + b3)
  k_mfma<<<dim3(157,1,RR), thr, 0, stream>>>(h, W3T, NN, 256, C34, 128,
                                             (long)NB256, 128*256, (long)NB128);
  k_aggp<1,0><<<gNode, thr, 0, stream>>>(C34, b3, off4, csr4, h3b, nullptr);
  // L4: C34[z] = h3[z] @ [Wrel4|Wroot4][z] ; out[:,z,:] = aggP + Q + b4
  k_mfma<<<dim3(157,1,RR), thr, 0, stream>>>(h3b, W4T, NN, 64, C34, 128,
                                             (long)NB64, 128*64, (long)NB128);
  k_aggp<0,1><<<gNode, thr, 0, stream>>>(C34, b4, off4, csr4, nullptr, out);
}